// Round 6
// baseline (1633.757 us; speedup 1.0000x reference)
//
#include <hip/hip_runtime.h>
#include <cstdint>
#include <cstddef>

#define NN 5000     // nodes per batch block
#define EE 40000    // edges per batch block
#define BATCH 8
#define SS 12
#define FF 16
#define HH 128
#define TOTAL 40000 // BATCH*NN
#define CC 4

// Layout: per-row state arrays use row = n*8 + bb (batch-interleaved). Gather-only
// message matrices are INT8 with one fp32 scale per source node per matrix.
//
// Fused schedule (per timestep): B cand0-GEMM, C gates1-GEMM, D cand1-GEMM,
// E gates0-GEMM(t+1); each kernel's PROLOGUE does the gather/aggregate of the
// previous GEMM's messages for its own 4 nodes. 32-row tiles, 512 threads.
//
// R6: (1) int8 quant directly from MFMA accumulators (no bf16/LDS round-trip,
// one barrier fewer); (2) u never hits global: C/E gather GqU on waves 4-7 and
// hand u to waves 0-3 via LDS f32[4][64][17] (odd stride -> conflict-free).
// Gates buffers split per layer (GqR0/GqU0, GqR1/GqU1) so no kernel reads a
// buffer its own epilogue writes (G16 cross-block race, proven in R2).

typedef __attribute__((ext_vector_type(8))) short short8;   // 8 bf16 (4 VGPRs)
typedef __attribute__((ext_vector_type(4))) float f32x4;    // 4 fp32

__device__ __forceinline__ unsigned short f2bf(float f) {
  union { float f; unsigned u; } v; v.f = f;
  unsigned r = v.u + 0x7fff + ((v.u >> 16) & 1);  // RTNE
  return (unsigned short)(r >> 16);
}
__device__ __forceinline__ float bf2f(unsigned short b) {
  union { unsigned u; float f; } v; v.u = ((unsigned)b) << 16;
  return v.f;
}
__device__ __forceinline__ float bflo(unsigned v) {
  union { unsigned u; float f; } x; x.u = v << 16; return x.f;
}
__device__ __forceinline__ float bfhi(unsigned v) {
  union { unsigned u; float f; } x; x.u = v & 0xffff0000u; return x.f;
}
// acc[0..15] += ws * (int8x16 from qv)
__device__ __forceinline__ void qfma16(float* acc, uint4 qv, float ws) {
  unsigned wd[4] = {qv.x, qv.y, qv.z, qv.w};
#pragma unroll
  for (int d = 0; d < 4; d++) {
#pragma unroll
    for (int k = 0; k < 4; k++) {
      int q = (int)((signed char)(wd[d] >> (8 * k)));
      acc[d * 4 + k] += ws * (float)q;
    }
  }
}

// Full-degree gather: one wave owns one (node, matrix) unit. 4-wide unroll.
// lane -> (bb = lane>>3, 16 feats at (lane&7)*16). acc[16] out.
__device__ __forceinline__ void gather_accum(const signed char* __restrict__ Gq,
                                             const float* __restrict__ sc,
                                             int e0, int e1,
                                             const int* __restrict__ csr_src,
                                             const float* __restrict__ csr_w,
                                             const float* __restrict__ dis,
                                             int n, int bb, int fo, float* acc) {
  float sn = dis[n]; sn *= sn;
  size_t rowSelf = (size_t)(n << 3) + bb;
#pragma unroll
  for (int k = 0; k < 16; k++) acc[k] = 0.f;
  {
    float ws = sn * sc[n];
    uint4 qv = *(const uint4*)&Gq[rowSelf * 128 + fo];
    qfma16(acc, qv, ws);
  }
  int e = e0;
  for (; e + 3 < e1; e += 4) {
    int s0 = csr_src[e], s1 = csr_src[e + 1];
    int s2 = csr_src[e + 2], s3 = csr_src[e + 3];
    float w0 = csr_w[e] * sc[s0];
    float w1 = csr_w[e + 1] * sc[s1];
    float w2 = csr_w[e + 2] * sc[s2];
    float w3 = csr_w[e + 3] * sc[s3];
    uint4 qa = *(const uint4*)&Gq[(((size_t)s0 << 3) + bb) * 128 + fo];
    uint4 qb = *(const uint4*)&Gq[(((size_t)s1 << 3) + bb) * 128 + fo];
    uint4 qc = *(const uint4*)&Gq[(((size_t)s2 << 3) + bb) * 128 + fo];
    uint4 qd = *(const uint4*)&Gq[(((size_t)s3 << 3) + bb) * 128 + fo];
    qfma16(acc, qa, w0);
    qfma16(acc, qb, w1);
    qfma16(acc, qc, w2);
    qfma16(acc, qd, w3);
  }
  for (; e < e1; e++) {
    int s0 = csr_src[e];
    float w0 = csr_w[e] * sc[s0];
    uint4 qa = *(const uint4*)&Gq[(((size_t)s0 << 3) + bb) * 128 + fo];
    qfma16(acc, qa, w0);
  }
}

// GRU combine with f32 u from LDS handoff:
// h_new = u*h + (1-u)*tanh(acc+b); writes h back to global; o0/o1 packed rows.
__device__ __forceinline__ void gru_combine_f32u(const float* acc, const float* bp,
                                                 const float* uv,
                                                 unsigned short* __restrict__ h_io,
                                                 size_t rowSelf, int fo,
                                                 uint4& o0, uint4& o1) {
  uint4 oo[2];
#pragma unroll
  for (int jj = 0; jj < 2; jj++) {
    uint4 hq = *(const uint4*)&h_io[rowSelf * 128 + fo + 8 * jj];
    float hv[8];
    hv[0] = bflo(hq.x); hv[1] = bfhi(hq.x); hv[2] = bflo(hq.y); hv[3] = bfhi(hq.y);
    hv[4] = bflo(hq.z); hv[5] = bfhi(hq.z); hv[6] = bflo(hq.w); hv[7] = bfhi(hq.w);
    unsigned ow[4];
#pragma unroll
    for (int d = 0; d < 4; d++) {
      float v0 = acc[8 * jj + 2 * d]     + bp[8 * jj + 2 * d];
      float v1 = acc[8 * jj + 2 * d + 1] + bp[8 * jj + 2 * d + 1];
      float c0 = 1.0f - 2.0f / (__expf(2.0f * v0) + 1.0f);  // tanh
      float c1 = 1.0f - 2.0f / (__expf(2.0f * v1) + 1.0f);
      float u0 = uv[8 * jj + 2 * d], u1 = uv[8 * jj + 2 * d + 1];
      float n0 = u0 * hv[2 * d] + (1.0f - u0) * c0;
      float n1 = u1 * hv[2 * d + 1] + (1.0f - u1) * c1;
      ow[d] = (unsigned)f2bf(n0) | ((unsigned)f2bf(n1) << 16);
    }
    oo[jj].x = ow[0]; oo[jj].y = ow[1]; oo[jj].z = ow[2]; oo[jj].w = ow[3];
    *(uint4*)&h_io[rowSelf * 128 + fo + 8 * jj] = oo[jj];
  }
  o0 = oo[0]; o1 = oo[1];
}

// ---------------- graph preprocessing (once per launch) ----------------

__global__ void deg_cnt_kernel(const int* __restrict__ ei, const float* __restrict__ ew,
                               float* __restrict__ deg, int* __restrict__ cnt) {
  int e = blockIdx.x * 256 + threadIdx.x;
  if (e < EE) {
    int col = ei[EE + e];
    atomicAdd(&deg[col], ew[e]);
    atomicAdd(&cnt[col], 1);
  }
}

__global__ void dis_kernel(const float* __restrict__ deg, float* __restrict__ dis) {
  int n = blockIdx.x * 256 + threadIdx.x;
  if (n < NN) dis[n] = rsqrtf(deg[n] + 1.0f);  // +1: self-loop weight
}

__global__ void scan_kernel(const int* __restrict__ cnt, int* __restrict__ offs) {
  __shared__ int part[256];
  const int CH = (NN + 255) / 256; // 20
  int tid = threadIdx.x;
  int base = tid * CH;
  int s = 0;
  for (int i = 0; i < CH; i++) { int idx = base + i; if (idx < NN) s += cnt[idx]; }
  part[tid] = s;
  __syncthreads();
  for (int off = 1; off < 256; off <<= 1) {
    int v = (tid >= off) ? part[tid - off] : 0;
    __syncthreads();
    part[tid] += v;
    __syncthreads();
  }
  int run = (tid == 0) ? 0 : part[tid - 1];
  for (int i = 0; i < CH; i++) {
    int idx = base + i;
    if (idx < NN) { offs[idx] = run; run += cnt[idx]; }
  }
  if (tid == 255) offs[NN] = run;
}

__global__ void fill_csr_kernel(const int* __restrict__ ei, const float* __restrict__ ew,
                                const float* __restrict__ dis, const int* __restrict__ offs,
                                int* __restrict__ cursor, int* __restrict__ csr_src,
                                float* __restrict__ csr_w) {
  int e = blockIdx.x * 256 + threadIdx.x;
  if (e < EE) {
    int row = ei[e], col = ei[EE + e];
    int pos = offs[col] + atomicAdd(&cursor[col], 1);
    csr_src[pos] = row;
    csr_w[pos] = dis[row] * ew[e] * dis[col];
  }
}

// ---------------- weight prepack: fp32 [k][n] -> bf16 MFMA b-frag order ----------------

__global__ void prepack_kernel(const float* __restrict__ convW, unsigned short* __restrict__ Wp) {
  int idx = blockIdx.x * 256 + threadIdx.x;  // 6*8*8*64 = 24576
  int lane = idx & 63;
  int ks = (idx >> 6) & 7;
  int nt = (idx >> 9) & 7;
  int g = idx >> 12;
  const float* W = convW + (size_t)g * 256 * 128;
  int n = nt * 16 + (lane & 15);
  int k0 = ks * 32 + (lane >> 4) * 8;
  unsigned short v[8];
#pragma unroll
  for (int j = 0; j < 8; j++) v[j] = f2bf(W[(size_t)(k0 + j) * 128 + n]);
  *(uint4*)(Wp + (size_t)idx * 8) = *(const uint4*)v;
}

// ---------------- lin_in (bootstrap t=0 only) ----------------

__global__ __launch_bounds__(256) void lin_in_kernel(const float* __restrict__ x_seq,
                                                     const float* __restrict__ W,
                                                     const float* __restrict__ b,
                                                     unsigned short* __restrict__ xt, int t) {
  int idx = blockIdx.x * 256 + threadIdx.x;   // over TOTAL*16
  int row = idx >> 4, fh = idx & 15;          // feats 8fh..8fh+7
  int n = row >> 3, bb = row & 7;
  const float* xp = x_seq + (((size_t)bb * SS + t) * NN + n) * FF;
  float4 a0 = *(const float4*)&b[fh * 8];
  float4 a1 = *(const float4*)&b[fh * 8 + 4];
#pragma unroll
  for (int ff = 0; ff < FF; ff++) {
    float xv = xp[ff];
    float4 w0 = *(const float4*)&W[ff * HH + fh * 8];
    float4 w1 = *(const float4*)&W[ff * HH + fh * 8 + 4];
    a0.x += xv * w0.x; a0.y += xv * w0.y; a0.z += xv * w0.z; a0.w += xv * w0.w;
    a1.x += xv * w1.x; a1.y += xv * w1.y; a1.z += xv * w1.z; a1.w += xv * w1.w;
  }
  uint4 o;
  o.x = (unsigned)f2bf(fmaxf(a0.x, 0.f)) | ((unsigned)f2bf(fmaxf(a0.y, 0.f)) << 16);
  o.y = (unsigned)f2bf(fmaxf(a0.z, 0.f)) | ((unsigned)f2bf(fmaxf(a0.w, 0.f)) << 16);
  o.z = (unsigned)f2bf(fmaxf(a1.x, 0.f)) | ((unsigned)f2bf(fmaxf(a1.y, 0.f)) << 16);
  o.w = (unsigned)f2bf(fmaxf(a1.z, 0.f)) | ((unsigned)f2bf(fmaxf(a1.w, 0.f)) << 16);
  *(uint4*)&xt[(size_t)row * 128 + fh * 8] = o;
}

// ---------------- shared GEMM body (32-row tile, 8 waves) ----------------
// As (32 x 256 bf16, stride 264) staged by caller (caller syncs). MFMA, then
// per-(node,half) absmax computed FROM ACCUMULATORS (shfl + gmax LDS reduce),
// then int8 quantize acc directly -> byte stores to global. gmax = float[32].

template <int MT, int NTW, int HALVES, int NTHREADS>
__device__ __forceinline__ void gemm_body(const unsigned short* As, float* gmax,
                                          const unsigned short* __restrict__ Wp,
                                          signed char* __restrict__ qA,
                                          signed char* __restrict__ qB,
                                          float* __restrict__ sA,
                                          float* __restrict__ sB,
                                          int rowBase, int tid) {
  constexpr int NWAVES = NTHREADS / 64;     // 8
  constexpr int WPG = NWAVES / HALVES;      // waves per half: 4 or 8
  static_assert(MT == 2, "node mapping assumes 32-row tile");
  int wv = tid >> 6, lane = tid & 63;
  int m = lane & 15, q = lane >> 4;
  f32x4 acc[MT][NTW];
#pragma unroll
  for (int i = 0; i < MT; i++)
#pragma unroll
    for (int j = 0; j < NTW; j++) acc[i][j] = (f32x4)(0.0f);
  const unsigned short* wbase = Wp + ((size_t)(wv * NTW) * 8 * 64 + lane) * 8;
#pragma unroll
  for (int ks = 0; ks < 8; ks++) {
    short8 a[MT];
#pragma unroll
    for (int mt = 0; mt < MT; mt++)
      a[mt] = *(const short8*)&As[(mt * 16 + m) * 264 + ks * 32 + q * 8];
#pragma unroll
    for (int nt = 0; nt < NTW; nt++) {
      short8 b = *(const short8*)(wbase + (size_t)(nt * 8 + ks) * 64 * 8);
#pragma unroll
      for (int mt = 0; mt < MT; mt++)
        acc[mt][nt] = __builtin_amdgcn_mfma_f32_16x16x32_bf16(a[mt], b, acc[mt][nt], 0, 0, 0);
    }
  }
  // Per-lane row->node mapping: rows mt*16+q*4+i; node = mt*2 + (q>>1).
  // mxa: this lane's max for node (q>>1) [mt=0]; mxb: node 2+(q>>1) [mt=1].
  float mxa = 0.f, mxb = 0.f;
#pragma unroll
  for (int nt = 0; nt < NTW; nt++)
#pragma unroll
    for (int i = 0; i < 4; i++) {
      mxa = fmaxf(mxa, fabsf(acc[0][nt][i]));
      mxb = fmaxf(mxb, fabsf(acc[1][nt][i]));
    }
  // reduce: lane0 accumulates lanes 0..31 (q>>1==0), lane32 accumulates 32..63
#pragma unroll
  for (int off = 16; off; off >>= 1) {
    mxa = fmaxf(mxa, __shfl_down(mxa, off));
    mxb = fmaxf(mxb, __shfl_down(mxb, off));
  }
  if (lane == 0)  { gmax[wv * 4 + 0] = mxa; gmax[wv * 4 + 2] = mxb; }
  if (lane == 32) { gmax[wv * 4 + 1] = mxa; gmax[wv * 4 + 3] = mxb; }
  __syncthreads();
  // global per-(node,half) scale
  if (tid < 4 * HALVES) {
    int node = (HALVES == 2) ? (tid >> 1) : tid;
    int half = (HALVES == 2) ? (tid & 1) : 0;
    float g = 0.f;
#pragma unroll
    for (int w = 0; w < WPG; w++) g = fmaxf(g, gmax[(half * WPG + w) * 4 + node]);
    float* sp = half ? sB : sA;
    sp[(rowBase >> 3) + node] = g * (1.0f / 127.0f);
  }
  // per-lane inverse scales for its two nodes
  int half = (HALVES == 2) ? (wv / WPG) : 0;
  int qh = q >> 1;
  float ga = 0.f, gb = 0.f;
#pragma unroll
  for (int w = 0; w < WPG; w++) {
    ga = fmaxf(ga, gmax[(half * WPG + w) * 4 + qh]);
    gb = fmaxf(gb, gmax[(half * WPG + w) * 4 + 2 + qh]);
  }
  float invA = (ga > 0.f) ? (127.0f / ga) : 0.f;
  float invB = (gb > 0.f) ? (127.0f / gb) : 0.f;
  // quantize acc directly -> byte stores (rows strided by 128B)
  signed char* qbase = (half ? qB : qA);
#pragma unroll
  for (int mt = 0; mt < MT; mt++) {
    float inv = mt ? invB : invA;
#pragma unroll
    for (int nt = 0; nt < NTW; nt++) {
      int colq = (wv * NTW + nt) * 16 + m - half * 128;
      signed char* dst = qbase + (size_t)(rowBase + mt * 16 + q * 4) * 128 + colq;
#pragma unroll
      for (int i = 0; i < 4; i++) {
        int qv = __float2int_rn(acc[mt][nt][i] * inv);
        dst[(size_t)i * 128] = (signed char)qv;
      }
    }
  }
}

// ---------------- bootstrap GEMM (stages both halves from global) ----------------

template <int NTW, int HALVES>
__global__ __launch_bounds__(512) void gemm_mfma_q(const unsigned short* __restrict__ A1,
                                                   const unsigned short* __restrict__ A2,
                                                   const unsigned short* __restrict__ Wp,
                                                   signed char* __restrict__ qA,
                                                   signed char* __restrict__ qB,
                                                   float* __restrict__ sA,
                                                   float* __restrict__ sB) {
  __shared__ unsigned short As[32 * 264];
  __shared__ float gmax[32];
  int rowBase = blockIdx.x * 32;
  int tid = threadIdx.x;
  for (int c = tid; c < 1024; c += 512) {
    int row = c >> 5; int rest = c & 31; int half = rest >> 4; int sub = rest & 15;
    const unsigned short* src = (half ? A2 : A1) + ((size_t)(rowBase + row) * 128 + sub * 8);
    *(uint4*)&As[row * 264 + half * 128 + sub * 8] = *(const uint4*)src;
  }
  __syncthreads();
  gemm_body<2, NTW, HALVES, 512>(As, gmax, Wp, qA, qB, sA, sB, rowBase, tid);
}

// ---------------- FUSED B/D: r-gather prologue + candidate GEMM ----------------
// Waves 0-3: gather r for node wv -> rh = sigmoid(r)*h -> LDS A2.
// Waves 4-7: stage A1 (xin). GEMM [A1|rh]*Wc -> Cq (direct int8 quant).

__global__ __launch_bounds__(512, 8) void fused_cand_q(
    const signed char* __restrict__ GqR, const float* __restrict__ sR,
    const int* __restrict__ offs, const int* __restrict__ csr_src,
    const float* __restrict__ csr_w, const float* __restrict__ dis,
    const float* __restrict__ bR, const unsigned short* __restrict__ h,
    const unsigned short* __restrict__ A1, const unsigned short* __restrict__ Wp,
    signed char* __restrict__ Cq, float* __restrict__ sC) {
  __shared__ unsigned short As[32 * 264];
  __shared__ float gmax[32];
  int tid = threadIdx.x;
  int wv = tid >> 6, lane = tid & 63;
  int rowBase = blockIdx.x * 32, gn0 = rowBase >> 3;
  int bb = lane >> 3, fo = (lane & 7) << 4;
  if (wv >= 4) {
    int t2 = tid - 256;
    for (int c = t2; c < 512; c += 256) {
      int row = c >> 4, sub = c & 15;
      *(uint4*)&As[row * 264 + sub * 8] =
          *(const uint4*)&A1[(size_t)(rowBase + row) * 128 + sub * 8];
    }
  } else {
    int node8 = wv;
    int n = gn0 + node8;
    int e0 = offs[n], e1 = offs[n + 1];
    float acc[16];
    gather_accum(GqR, sR, e0, e1, csr_src, csr_w, dis, n, bb, fo, acc);
    size_t rowSelf = ((size_t)n << 3) + bb;
    int lr = node8 * 8 + bb;
#pragma unroll
    for (int jj = 0; jj < 2; jj++) {
      uint4 hq = *(const uint4*)&h[rowSelf * 128 + fo + 8 * jj];
      float hv[8];
      hv[0] = bflo(hq.x); hv[1] = bfhi(hq.x); hv[2] = bflo(hq.y); hv[3] = bfhi(hq.y);
      hv[4] = bflo(hq.z); hv[5] = bfhi(hq.z); hv[6] = bflo(hq.w); hv[7] = bfhi(hq.w);
      unsigned ow[4];
#pragma unroll
      for (int d = 0; d < 4; d++) {
        float s0 = 1.0f / (1.0f + __expf(-(acc[8 * jj + 2 * d]     + bR[fo + 8 * jj + 2 * d])));
        float s1 = 1.0f / (1.0f + __expf(-(acc[8 * jj + 2 * d + 1] + bR[fo + 8 * jj + 2 * d + 1])));
        ow[d] = (unsigned)f2bf(s0 * hv[2 * d]) | ((unsigned)f2bf(s1 * hv[2 * d + 1]) << 16);
      }
      uint4 o; o.x = ow[0]; o.y = ow[1]; o.z = ow[2]; o.w = ow[3];
      *(uint4*)&As[lr * 264 + 128 + fo + 8 * jj] = o;
    }
  }
  __syncthreads();
  gemm_body<2, 1, 1, 512>(As, gmax, Wp, Cq, Cq, sC, sC, rowBase, tid);
}

// ---------------- FUSED C: cand+u gather + GRU + gates GEMM ----------------
// Waves 0-3: cand-gather node wv. Waves 4-7: u-gather node wv-4 (GqU) ->
// uls handoff. After sync: waves 0-3 GRU -> h global + LDS A1; waves 4-7
// stage A2. GEMM [h_new|A2]*Wg -> next gates (split-layer buffers).

__global__ __launch_bounds__(512, 8) void fused_gates_q(
    const signed char* __restrict__ Cq, const float* __restrict__ sC,
    const signed char* __restrict__ GqU, const float* __restrict__ sU,
    const int* __restrict__ offs, const int* __restrict__ csr_src,
    const float* __restrict__ csr_w, const float* __restrict__ dis,
    const float* __restrict__ bC, const float* __restrict__ bU,
    unsigned short* __restrict__ h_io,
    const unsigned short* __restrict__ A2src, const unsigned short* __restrict__ Wp,
    signed char* __restrict__ GqRo, signed char* __restrict__ GqUo,
    float* __restrict__ sRo, float* __restrict__ sUo) {
  __shared__ unsigned short As[32 * 264];
  __shared__ float uls[4][64][17];   // odd stride -> conflict-free
  __shared__ float gmax[32];
  int tid = threadIdx.x;
  int wv = tid >> 6, lane = tid & 63;
  int rowBase = blockIdx.x * 32, gn0 = rowBase >> 3;
  int bb = lane >> 3, fo = (lane & 7) << 4;
  int node8 = wv & 3;
  int n = gn0 + node8;
  int e0 = offs[n], e1 = offs[n + 1];
  float acc[16];
  if (wv < 4) {
    gather_accum(Cq, sC, e0, e1, csr_src, csr_w, dis, n, bb, fo, acc);
  } else {
    gather_accum(GqU, sU, e0, e1, csr_src, csr_w, dis, n, bb, fo, acc);
#pragma unroll
    for (int k = 0; k < 16; k++)
      uls[node8][lane][k] = 1.0f / (1.0f + __expf(-(acc[k] + bU[fo + k])));
  }
  __syncthreads();
  if (wv < 4) {
    float uv[16];
#pragma unroll
    for (int k = 0; k < 16; k++) uv[k] = uls[node8][lane][k];
    size_t rowSelf = ((size_t)n << 3) + bb;
    uint4 o0, o1;
    gru_combine_f32u(acc, bC + fo, uv, h_io, rowSelf, fo, o0, o1);
    int lr = node8 * 8 + bb;
    *(uint4*)&As[lr * 264 + fo] = o0;
    *(uint4*)&As[lr * 264 + fo + 8] = o1;
  } else {
    int t2 = tid - 256;
    for (int c = t2; c < 512; c += 256) {
      int row = c >> 4, sub = c & 15;
      *(uint4*)&As[row * 264 + 128 + sub * 8] =
          *(const uint4*)&A2src[(size_t)(rowBase + row) * 128 + sub * 8];
    }
  }
  __syncthreads();
  gemm_body<2, 2, 2, 512>(As, gmax, Wp, GqRo, GqUo, sRo, sUo, rowBase, tid);
}

// ---------------- FUSED E: cand+u gather + h1 GRU + lin_in(t+1) + gates0 GEMM ----

__global__ __launch_bounds__(512, 8) void fused_gates_lin_q(
    const signed char* __restrict__ Cq, const float* __restrict__ sC,
    const signed char* __restrict__ GqU, const float* __restrict__ sU,
    const int* __restrict__ offs, const int* __restrict__ csr_src,
    const float* __restrict__ csr_w, const float* __restrict__ dis,
    const float* __restrict__ bC, const float* __restrict__ bU,
    unsigned short* __restrict__ h_io,
    const float* __restrict__ x_seq, const float* __restrict__ Win,
    const float* __restrict__ bin, unsigned short* __restrict__ xt_out,
    const unsigned short* __restrict__ A2src, const unsigned short* __restrict__ Wp,
    signed char* __restrict__ GqRo, signed char* __restrict__ GqUo,
    float* __restrict__ sRo, float* __restrict__ sUo, int t_next) {
  __shared__ unsigned short As[32 * 264];
  __shared__ float uls[4][64][17];
  __shared__ float gmax[32];
  int tid = threadIdx.x;
  int wv = tid >> 6, lane = tid & 63;
  int rowBase = blockIdx.x * 32, gn0 = rowBase >> 3;
  int bb = lane >> 3, fo = (lane & 7) << 4;
  int node8 = wv & 3;
  int n = gn0 + node8;
  int e0 = offs[n], e1 = offs[n + 1];
  float acc[16];
  if (wv < 4) {
    gather_accum(Cq, sC, e0, e1, csr_src, csr_w, dis, n, bb, fo, acc);
  } else {
    gather_accum(GqU, sU, e0, e1, csr_src, csr_w, dis, n, bb, fo, acc);
#pragma unroll
    for (int k = 0; k < 16; k++)
      uls[node8][lane][k] = 1.0f / (1.0f + __expf(-(acc[k] + bU[fo + k])));
  }
  __syncthreads();
  if (wv < 4) {
    float uv[16];
#pragma unroll
    for (int k = 0; k < 16; k++) uv[k] = uls[node8][lane][k];
    size_t rowSelf = ((size_t)n << 3) + bb;
    uint4 o0, o1;
    gru_combine_f32u(acc, bC + fo, uv, h_io, rowSelf, fo, o0, o1);
  } else {
    int t2 = tid - 256;
    // stage A2 (h0) into cols 128..255
    for (int c = t2; c < 512; c += 256) {
      int row = c >> 4, sub = c & 15;
      *(uint4*)&As[row * 264 + 128 + sub * 8] =
          *(const uint4*)&A2src[(size_t)(rowBase + row) * 128 + sub * 8];
    }
    // lin_in for t_next: 32 rows x 16 fh-units -> LDS cols 0..127 + global xt
    for (int c = t2; c < 512; c += 256) {
      int row = c >> 4, fh = c & 15;
      int grow = rowBase + row;
      int n2 = grow >> 3, bbv = grow & 7;
      const float* xp = x_seq + (((size_t)bbv * SS + t_next) * NN + n2) * FF;
      float4 a0 = *(const float4*)&bin[fh * 8];
      float4 a1 = *(const float4*)&bin[fh * 8 + 4];
#pragma unroll
      for (int ff = 0; ff < FF; ff++) {
        float xv = xp[ff];
        float4 w0 = *(const float4*)&Win[ff * HH + fh * 8];
        float4 w1 = *(const float4*)&Win[ff * HH + fh * 8 + 4];
        a0.x += xv * w0.x; a0.y += xv * w0.y; a0.z += xv * w0.z; a0.w += xv * w0.w;
        a1.x += xv * w1.x; a1.y += xv * w1.y; a1.z += xv * w1.z; a1.w += xv * w1.w;
      }
      uint4 o;
      o.x = (unsigned)f2bf(fmaxf(a0.x, 0.f)) | ((unsigned)f2bf(fmaxf(a0.y, 0.f)) << 16);
      o.y = (unsigned)f2bf(fmaxf(a0.z, 0.f)) | ((unsigned)f2bf(fmaxf(a0.w, 0.f)) << 16);
      o.z = (unsigned)f2bf(fmaxf(a1.x, 0.f)) | ((unsigned)f2bf(fmaxf(a1.y, 0.f)) << 16);
      o.w = (unsigned)f2bf(fmaxf(a1.z, 0.f)) | ((unsigned)f2bf(fmaxf(a1.w, 0.f)) << 16);
      *(uint4*)&As[row * 264 + fh * 8] = o;
      *(uint4*)&xt_out[(size_t)grow * 128 + fh * 8] = o;
    }
  }
  __syncthreads();
  gemm_body<2, 2, 2, 512>(As, gmax, Wp, GqRo, GqUo, sRo, sUo, rowBase, tid);
}

// ---------------- final step (t=S-1, layer 1): cand+u gather + GRU only --------

__global__ __launch_bounds__(256) void scatter_c_update2(
    const signed char* __restrict__ Cq, const float* __restrict__ sC,
    const signed char* __restrict__ GqU, const float* __restrict__ sU,
    const int* __restrict__ offs, const int* __restrict__ csr_src,
    const float* __restrict__ csr_w, const float* __restrict__ dis,
    const float* __restrict__ bC, const float* __restrict__ bU,
    unsigned short* __restrict__ h) {
  __shared__ float uls[2][64][17];
  int tid = threadIdx.x;
  int wv = tid >> 6, lane = tid & 63;
  int which = wv & 1;
  int n = blockIdx.x * 2 + which;
  int bb = lane >> 3;
  int fo = (lane & 7) << 4;
  int e0 = offs[n], e1 = offs[n + 1];
  float acc[16];
  if (wv < 2) {
    gather_accum(Cq, sC, e0, e1, csr_src, csr_w, dis, n, bb, fo, acc);
  } else {
    gather_accum(GqU, sU, e0, e1, csr_src, csr_w, dis, n, bb, fo, acc);
#pragma unroll
    for (int k = 0; k < 16; k++)
      uls[which][lane][k] = 1.0f / (1.0f + __expf(-(acc[k] + bU[fo + k])));
  }
  __syncthreads();
  if (wv < 2) {
    float uv[16];
#pragma unroll
    for (int k = 0; k < 16; k++) uv[k] = uls[which][lane][k];
    size_t rowSelf = (size_t)(n << 3) + bb;
    uint4 o0, o1;
    gru_combine_f32u(acc, bC + fo, uv, h, rowSelf, fo, o0, o1);
  }
}

// ---------------- BatchNorm stats ----------------

__global__ __launch_bounds__(256) void bn_stats_kernel(const unsigned short* __restrict__ h,
                                                       float* __restrict__ sums) {
  __shared__ float ls[512];
  int tid = threadIdx.x;
  float s = 0.f, sq = 0.f;
  for (size_t idx = (size_t)blockIdx.x * 256 + tid; idx < (size_t)TOTAL * HH;
       idx += (size_t)gridDim.x * 256) {
    float v = bf2f(h[idx]);
    s += v; sq += v * v;
  }
  ls[tid] = s; ls[256 + tid] = sq;
  __syncthreads();
  if (tid < 128) {
    atomicAdd(&sums[tid], ls[tid] + ls[tid + 128]);
    atomicAdd(&sums[128 + tid], ls[256 + tid] + ls[256 + tid + 128]);
  }
}

// ---------------- fused BN -> relu -> lin_out -> log_softmax ----------------

__global__ __launch_bounds__(256) void final_kernel(const unsigned short* __restrict__ h,
                                                    const float* __restrict__ sums,
                                                    const float* __restrict__ gamma,
                                                    const float* __restrict__ beta,
                                                    const float* __restrict__ Wout,
                                                    const float* __restrict__ bout,
                                                    float* __restrict__ out) {
  int wid = threadIdx.x >> 6, lane = threadIdx.x & 63;
  int row = blockIdx.x * 4 + wid; // node-row (n*8+bb order)
  if (row >= TOTAL) return;
  const float inv = 1.0f / (float)TOTAL;
  float p0 = 0.f, p1 = 0.f, p2 = 0.f, p3 = 0.f;
#pragma unroll
  for (int jj = 0; jj < 2; jj++) {
    int j = lane + jj * 64;
    float mean = sums[j] * inv;
    float var = sums[128 + j] * inv - mean * mean;
    float hn = (bf2f(h[(size_t)row * HH + j]) - mean) * rsqrtf(var + 1e-5f) * gamma[j] + beta[j];
    hn = fmaxf(hn, 0.0f);
    p0 += hn * Wout[j * 4 + 0];
    p1 += hn * Wout[j * 4 + 1];
    p2 += hn * Wout[j * 4 + 2];
    p3 += hn * Wout[j * 4 + 3];
  }
  for (int off = 32; off; off >>= 1) {
    p0 += __shfl_down(p0, off);
    p1 += __shfl_down(p1, off);
    p2 += __shfl_down(p2, off);
    p3 += __shfl_down(p3, off);
  }
  if (lane == 0) {
    p0 += bout[0]; p1 += bout[1]; p2 += bout[2]; p3 += bout[3];
    float m = fmaxf(fmaxf(p0, p1), fmaxf(p2, p3));
    float e = __expf(p0 - m) + __expf(p1 - m) + __expf(p2 - m) + __expf(p3 - m);
    float lse = m + __logf(e);
    int bb = row & 7, n = row >> 3;
    float* o = out + ((size_t)bb * NN + n) * 4;
    o[0] = p0 - lse; o[1] = p1 - lse; o[2] = p2 - lse; o[3] = p3 - lse;
  }
}

// ---------------- launcher ----------------

extern "C" void kernel_launch(void* const* d_in, const int* in_sizes, int n_in,
                              void* d_out, int out_size, void* d_ws, size_t ws_size,
                              hipStream_t stream) {
  const float* x_seq = (const float*)d_in[0];
  const int* ei      = (const int*)d_in[1];
  const float* ew    = (const float*)d_in[2];
  const float* Win   = (const float*)d_in[3];
  const float* bin   = (const float*)d_in[4];
  const float* convW = (const float*)d_in[5];
  const float* convB = (const float*)d_in[6];
  const float* gamma = (const float*)d_in[7];
  const float* beta  = (const float*)d_in[8];
  const float* Wout  = (const float*)d_in[9];
  const float* bout  = (const float*)d_in[10];
  float* out = (float*)d_out;

  char* ws = (char*)d_ws;
  size_t off = 0;
  auto alloc = [&](size_t bytes) {
    void* p = ws + off;
    off += (bytes + 1023) & ~(size_t)1023;
    return p;
  };
  float* deg     = (float*)alloc(NN * 4);
  float* dis     = (float*)alloc(NN * 4);
  int*   cnt     = (int*)alloc(NN * 4);
  int*   offs    = (int*)alloc((NN + 1) * 4);
  int*   cursor  = (int*)alloc(NN * 4);
  int*   csr_src = (int*)alloc(EE * 4);
  float* csr_w   = (float*)alloc(EE * 4);
  float* sums    = (float*)alloc(256 * 4);
  float* sR0     = (float*)alloc(NN * 4);
  float* sU0     = (float*)alloc(NN * 4);
  float* sR1     = (float*)alloc(NN * 4);
  float* sU1     = (float*)alloc(NN * 4);
  float* sC      = (float*)alloc(NN * 4);
  unsigned short* Wp = (unsigned short*)alloc(6 * 32768 * 2);  // packed conv weights
  const size_t NH = (size_t)TOTAL * HH; // 5,120,000
  unsigned short* h0 = (unsigned short*)alloc(NH * 2);
  unsigned short* h1 = (unsigned short*)alloc(NH * 2);
  unsigned short* xt = (unsigned short*)alloc(NH * 2);
  signed char* GqR0 = (signed char*)alloc(NH);  // per-layer gates message buffers
  signed char* GqU0 = (signed char*)alloc(NH);
  signed char* GqR1 = (signed char*)alloc(NH);
  signed char* GqU1 = (signed char*)alloc(NH);
  signed char* Cq   = (signed char*)alloc(NH);  // candidate messages (dedicated)

  hipMemsetAsync(deg, 0, NN * 4, stream);
  hipMemsetAsync(cnt, 0, NN * 4, stream);
  hipMemsetAsync(cursor, 0, NN * 4, stream);
  hipMemsetAsync(sums, 0, 256 * 4, stream);
  hipMemsetAsync(h0, 0, NH * 2, stream);
  hipMemsetAsync(h1, 0, NH * 2, stream);

  deg_cnt_kernel<<<(EE + 255) / 256, 256, 0, stream>>>(ei, ew, deg, cnt);
  dis_kernel<<<(NN + 255) / 256, 256, 0, stream>>>(deg, dis);
  scan_kernel<<<1, 256, 0, stream>>>(cnt, offs);
  fill_csr_kernel<<<(EE + 255) / 256, 256, 0, stream>>>(ei, ew, dis, offs, cursor, csr_src, csr_w);
  prepack_kernel<<<24576 / 256, 256, 0, stream>>>(convW, Wp);

  const unsigned short* Wg0 = Wp;
  const unsigned short* Wc0 = Wp + (size_t)2 * 32768;
  const unsigned short* Wg1 = Wp + (size_t)3 * 32768;
  const unsigned short* Wc1 = Wp + (size_t)5 * 32768;
  const float* bR0 = convB;                 // layer-0 r bias
  const float* bU0 = convB + 128;           // layer-0 u bias
  const float* bC0 = convB + 2 * HH;
  const float* bR1 = convB + 3 * HH;
  const float* bU1 = convB + 3 * HH + 128;
  const float* bC1 = convB + 5 * HH;

  // bootstrap: xt(t=0), gates0(t=0)
  lin_in_kernel<<<TOTAL * 16 / 256, 256, 0, stream>>>(x_seq, Win, bin, xt, 0);
  gemm_mfma_q<2, 2><<<TOTAL / 32, 512, 0, stream>>>(xt, h0, Wg0, GqR0, GqU0, sR0, sU0);

  for (int t = 0; t < SS; t++) {
    // B: r0-gather -> rh0(LDS); cand0 GEMM -> Cq
    fused_cand_q<<<TOTAL / 32, 512, 0, stream>>>(GqR0, sR0, offs, csr_src, csr_w, dis,
                                                 bR0, h0, xt, Wc0, Cq, sC);
    // C: cand0 + u0 gather -> h0 update -> gates1 GEMM -> GqR1/GqU1
    fused_gates_q<<<TOTAL / 32, 512, 0, stream>>>(Cq, sC, GqU0, sU0, offs, csr_src, csr_w,
                                                  dis, bC0, bU0, h0, h1, Wg1,
                                                  GqR1, GqU1, sR1, sU1);
    // D: r1-gather -> rh1(LDS); cand1 GEMM -> Cq
    fused_cand_q<<<TOTAL / 32, 512, 0, stream>>>(GqR1, sR1, offs, csr_src, csr_w, dis,
                                                 bR1, h1, h0, Wc1, Cq, sC);
    // E: cand1 + u1 gather -> h1 update; lin_in(t+1) -> xt; gates0 GEMM -> GqR0/GqU0
    if (t < SS - 1) {
      fused_gates_lin_q<<<TOTAL / 32, 512, 0, stream>>>(Cq, sC, GqU1, sU1, offs, csr_src,
                                                        csr_w, dis, bC1, bU1, h1,
                                                        x_seq, Win, bin, xt, h0, Wg0,
                                                        GqR0, GqU0, sR0, sU0, t + 1);
    } else {
      scatter_c_update2<<<NN / 2, 256, 0, stream>>>(Cq, sC, GqU1, sU1, offs, csr_src,
                                                    csr_w, dis, bC1, bU1, h1);
    }
  }

  bn_stats_kernel<<<256, 256, 0, stream>>>(h1, sums);
  final_kernel<<<TOTAL / 4, 256, 0, stream>>>(h1, sums, gamma, beta, Wout, bout, out);
}

// Round 7
// 1557.373 us; speedup vs baseline: 1.0490x; 1.0490x over previous
//
#include <hip/hip_runtime.h>
#include <cstdint>
#include <cstddef>

#define NN 5000     // nodes per batch block
#define EE 40000    // edges per batch block
#define BATCH 8
#define SS 12
#define FF 16
#define HH 128
#define TOTAL 40000 // BATCH*NN
#define CC 4

// Layout: per-row state arrays use row = n*8 + bb (batch-interleaved). Gather-only
// message matrices are INT8 with one fp32 scale per source node per matrix.
//
// Fused schedule (R5 structure, best-known): B cand0-GEMM, C gates1-GEMM,
// D cand1-GEMM, E gates0-GEMM(+lin_in t+1). Each kernel's PROLOGUE gathers the
// previous GEMM's messages for its own 4 nodes. 32-row tiles, 512 threads.
//  - B/D: 8 gather units (4 nodes x {r,u}) one per wave; u -> global (ub).
//  - C/E: 4 cand-gather units waves 0-3; waves 4-7 stage A2 (+ lin_in in E).
//    (R6's u-gather-in-C/E REGRESSED: +13MB random FETCH, longer prologue.)
//
// R7: direct int8 quant from MFMA accumulators (kept from R6, isolated):
// per-(node,half) absmax via register reduce + 128B gmax LDS, quantize acc
// straight to byte stores. Removes Cs (17KB LDS), one barrier, bf16 roundtrip.
//
// CORRECTNESS (G16): Cq dedicated (not aliasing GqR) — cross-block race at
// grid > co-residency, proven in R2.

typedef __attribute__((ext_vector_type(8))) short short8;   // 8 bf16 (4 VGPRs)
typedef __attribute__((ext_vector_type(4))) float f32x4;    // 4 fp32

__device__ __forceinline__ unsigned short f2bf(float f) {
  union { float f; unsigned u; } v; v.f = f;
  unsigned r = v.u + 0x7fff + ((v.u >> 16) & 1);  // RTNE
  return (unsigned short)(r >> 16);
}
__device__ __forceinline__ float bf2f(unsigned short b) {
  union { unsigned u; float f; } v; v.u = ((unsigned)b) << 16;
  return v.f;
}
__device__ __forceinline__ float bflo(unsigned v) {
  union { unsigned u; float f; } x; x.u = v << 16; return x.f;
}
__device__ __forceinline__ float bfhi(unsigned v) {
  union { unsigned u; float f; } x; x.u = v & 0xffff0000u; return x.f;
}
// acc[0..15] += ws * (int8x16 from qv)
__device__ __forceinline__ void qfma16(float* acc, uint4 qv, float ws) {
  unsigned wd[4] = {qv.x, qv.y, qv.z, qv.w};
#pragma unroll
  for (int d = 0; d < 4; d++) {
#pragma unroll
    for (int k = 0; k < 4; k++) {
      int q = (int)((signed char)(wd[d] >> (8 * k)));
      acc[d * 4 + k] += ws * (float)q;
    }
  }
}

// Full-degree gather: one wave owns one (node, matrix) unit. 4-wide unroll.
// lane -> (bb = lane>>3, 16 feats at (lane&7)*16). acc[16] out.
__device__ __forceinline__ void gather_accum(const signed char* __restrict__ Gq,
                                             const float* __restrict__ sc,
                                             int e0, int e1,
                                             const int* __restrict__ csr_src,
                                             const float* __restrict__ csr_w,
                                             const float* __restrict__ dis,
                                             int n, int bb, int fo, float* acc) {
  float sn = dis[n]; sn *= sn;
  size_t rowSelf = (size_t)(n << 3) + bb;
#pragma unroll
  for (int k = 0; k < 16; k++) acc[k] = 0.f;
  {
    float ws = sn * sc[n];
    uint4 qv = *(const uint4*)&Gq[rowSelf * 128 + fo];
    qfma16(acc, qv, ws);
  }
  int e = e0;
  for (; e + 3 < e1; e += 4) {
    int s0 = csr_src[e], s1 = csr_src[e + 1];
    int s2 = csr_src[e + 2], s3 = csr_src[e + 3];
    float w0 = csr_w[e] * sc[s0];
    float w1 = csr_w[e + 1] * sc[s1];
    float w2 = csr_w[e + 2] * sc[s2];
    float w3 = csr_w[e + 3] * sc[s3];
    uint4 qa = *(const uint4*)&Gq[(((size_t)s0 << 3) + bb) * 128 + fo];
    uint4 qb = *(const uint4*)&Gq[(((size_t)s1 << 3) + bb) * 128 + fo];
    uint4 qc = *(const uint4*)&Gq[(((size_t)s2 << 3) + bb) * 128 + fo];
    uint4 qd = *(const uint4*)&Gq[(((size_t)s3 << 3) + bb) * 128 + fo];
    qfma16(acc, qa, w0);
    qfma16(acc, qb, w1);
    qfma16(acc, qc, w2);
    qfma16(acc, qd, w3);
  }
  for (; e < e1; e++) {
    int s0 = csr_src[e];
    float w0 = csr_w[e] * sc[s0];
    uint4 qa = *(const uint4*)&Gq[(((size_t)s0 << 3) + bb) * 128 + fo];
    qfma16(acc, qa, w0);
  }
}

// GRU combine, 8-element chunks (low register pressure), u from global bf16:
// h_new = u*h + (1-u)*tanh(acc+b); writes h back to global; o0/o1 packed rows.
__device__ __forceinline__ void gru_combine_store(const float* acc, const float* bp,
                                                  const unsigned short* __restrict__ u_in,
                                                  unsigned short* __restrict__ h_io,
                                                  size_t rowSelf, int fo,
                                                  uint4& o0, uint4& o1) {
  uint4 oo[2];
#pragma unroll
  for (int jj = 0; jj < 2; jj++) {
    uint4 uq = *(const uint4*)&u_in[rowSelf * 128 + fo + 8 * jj];
    uint4 hq = *(const uint4*)&h_io[rowSelf * 128 + fo + 8 * jj];
    float uv[8], hv[8];
    uv[0] = bflo(uq.x); uv[1] = bfhi(uq.x); uv[2] = bflo(uq.y); uv[3] = bfhi(uq.y);
    uv[4] = bflo(uq.z); uv[5] = bfhi(uq.z); uv[6] = bflo(uq.w); uv[7] = bfhi(uq.w);
    hv[0] = bflo(hq.x); hv[1] = bfhi(hq.x); hv[2] = bflo(hq.y); hv[3] = bfhi(hq.y);
    hv[4] = bflo(hq.z); hv[5] = bfhi(hq.z); hv[6] = bflo(hq.w); hv[7] = bfhi(hq.w);
    unsigned ow[4];
#pragma unroll
    for (int d = 0; d < 4; d++) {
      float v0 = acc[8 * jj + 2 * d]     + bp[8 * jj + 2 * d];
      float v1 = acc[8 * jj + 2 * d + 1] + bp[8 * jj + 2 * d + 1];
      float c0 = 1.0f - 2.0f / (__expf(2.0f * v0) + 1.0f);  // tanh
      float c1 = 1.0f - 2.0f / (__expf(2.0f * v1) + 1.0f);
      float n0 = uv[2 * d] * hv[2 * d] + (1.0f - uv[2 * d]) * c0;
      float n1 = uv[2 * d + 1] * hv[2 * d + 1] + (1.0f - uv[2 * d + 1]) * c1;
      ow[d] = (unsigned)f2bf(n0) | ((unsigned)f2bf(n1) << 16);
    }
    oo[jj].x = ow[0]; oo[jj].y = ow[1]; oo[jj].z = ow[2]; oo[jj].w = ow[3];
    *(uint4*)&h_io[rowSelf * 128 + fo + 8 * jj] = oo[jj];
  }
  o0 = oo[0]; o1 = oo[1];
}

// ---------------- graph preprocessing (once per launch) ----------------

__global__ void deg_cnt_kernel(const int* __restrict__ ei, const float* __restrict__ ew,
                               float* __restrict__ deg, int* __restrict__ cnt) {
  int e = blockIdx.x * 256 + threadIdx.x;
  if (e < EE) {
    int col = ei[EE + e];
    atomicAdd(&deg[col], ew[e]);
    atomicAdd(&cnt[col], 1);
  }
}

__global__ void dis_kernel(const float* __restrict__ deg, float* __restrict__ dis) {
  int n = blockIdx.x * 256 + threadIdx.x;
  if (n < NN) dis[n] = rsqrtf(deg[n] + 1.0f);  // +1: self-loop weight
}

__global__ void scan_kernel(const int* __restrict__ cnt, int* __restrict__ offs) {
  __shared__ int part[256];
  const int CH = (NN + 255) / 256; // 20
  int tid = threadIdx.x;
  int base = tid * CH;
  int s = 0;
  for (int i = 0; i < CH; i++) { int idx = base + i; if (idx < NN) s += cnt[idx]; }
  part[tid] = s;
  __syncthreads();
  for (int off = 1; off < 256; off <<= 1) {
    int v = (tid >= off) ? part[tid - off] : 0;
    __syncthreads();
    part[tid] += v;
    __syncthreads();
  }
  int run = (tid == 0) ? 0 : part[tid - 1];
  for (int i = 0; i < CH; i++) {
    int idx = base + i;
    if (idx < NN) { offs[idx] = run; run += cnt[idx]; }
  }
  if (tid == 255) offs[NN] = run;
}

__global__ void fill_csr_kernel(const int* __restrict__ ei, const float* __restrict__ ew,
                                const float* __restrict__ dis, const int* __restrict__ offs,
                                int* __restrict__ cursor, int* __restrict__ csr_src,
                                float* __restrict__ csr_w) {
  int e = blockIdx.x * 256 + threadIdx.x;
  if (e < EE) {
    int row = ei[e], col = ei[EE + e];
    int pos = offs[col] + atomicAdd(&cursor[col], 1);
    csr_src[pos] = row;
    csr_w[pos] = dis[row] * ew[e] * dis[col];
  }
}

// ---------------- weight prepack: fp32 [k][n] -> bf16 MFMA b-frag order ----------------

__global__ void prepack_kernel(const float* __restrict__ convW, unsigned short* __restrict__ Wp) {
  int idx = blockIdx.x * 256 + threadIdx.x;  // 6*8*8*64 = 24576
  int lane = idx & 63;
  int ks = (idx >> 6) & 7;
  int nt = (idx >> 9) & 7;
  int g = idx >> 12;
  const float* W = convW + (size_t)g * 256 * 128;
  int n = nt * 16 + (lane & 15);
  int k0 = ks * 32 + (lane >> 4) * 8;
  unsigned short v[8];
#pragma unroll
  for (int j = 0; j < 8; j++) v[j] = f2bf(W[(size_t)(k0 + j) * 128 + n]);
  *(uint4*)(Wp + (size_t)idx * 8) = *(const uint4*)v;
}

// ---------------- lin_in (bootstrap t=0 only) ----------------

__global__ __launch_bounds__(256) void lin_in_kernel(const float* __restrict__ x_seq,
                                                     const float* __restrict__ W,
                                                     const float* __restrict__ b,
                                                     unsigned short* __restrict__ xt, int t) {
  int idx = blockIdx.x * 256 + threadIdx.x;   // over TOTAL*16
  int row = idx >> 4, fh = idx & 15;          // feats 8fh..8fh+7
  int n = row >> 3, bb = row & 7;
  const float* xp = x_seq + (((size_t)bb * SS + t) * NN + n) * FF;
  float4 a0 = *(const float4*)&b[fh * 8];
  float4 a1 = *(const float4*)&b[fh * 8 + 4];
#pragma unroll
  for (int ff = 0; ff < FF; ff++) {
    float xv = xp[ff];
    float4 w0 = *(const float4*)&W[ff * HH + fh * 8];
    float4 w1 = *(const float4*)&W[ff * HH + fh * 8 + 4];
    a0.x += xv * w0.x; a0.y += xv * w0.y; a0.z += xv * w0.z; a0.w += xv * w0.w;
    a1.x += xv * w1.x; a1.y += xv * w1.y; a1.z += xv * w1.z; a1.w += xv * w1.w;
  }
  uint4 o;
  o.x = (unsigned)f2bf(fmaxf(a0.x, 0.f)) | ((unsigned)f2bf(fmaxf(a0.y, 0.f)) << 16);
  o.y = (unsigned)f2bf(fmaxf(a0.z, 0.f)) | ((unsigned)f2bf(fmaxf(a0.w, 0.f)) << 16);
  o.z = (unsigned)f2bf(fmaxf(a1.x, 0.f)) | ((unsigned)f2bf(fmaxf(a1.y, 0.f)) << 16);
  o.w = (unsigned)f2bf(fmaxf(a1.z, 0.f)) | ((unsigned)f2bf(fmaxf(a1.w, 0.f)) << 16);
  *(uint4*)&xt[(size_t)row * 128 + fh * 8] = o;
}

// ---------------- shared GEMM body (32-row tile, 8 waves) ----------------
// As (32 x 256 bf16, stride 264) staged by caller (caller syncs). MFMA, then
// per-(node,half) absmax computed FROM ACCUMULATORS (shfl + gmax LDS reduce),
// then int8 quantize acc directly -> byte stores to global. gmax = float[32].

template <int MT, int NTW, int HALVES, int NTHREADS>
__device__ __forceinline__ void gemm_body(const unsigned short* As, float* gmax,
                                          const unsigned short* __restrict__ Wp,
                                          signed char* __restrict__ qA,
                                          signed char* __restrict__ qB,
                                          float* __restrict__ sA,
                                          float* __restrict__ sB,
                                          int rowBase, int tid) {
  constexpr int NWAVES = NTHREADS / 64;     // 8
  constexpr int WPG = NWAVES / HALVES;      // waves per half: 4 or 8
  static_assert(MT == 2, "node mapping assumes 32-row tile");
  int wv = tid >> 6, lane = tid & 63;
  int m = lane & 15, q = lane >> 4;
  f32x4 acc[MT][NTW];
#pragma unroll
  for (int i = 0; i < MT; i++)
#pragma unroll
    for (int j = 0; j < NTW; j++) acc[i][j] = (f32x4)(0.0f);
  const unsigned short* wbase = Wp + ((size_t)(wv * NTW) * 8 * 64 + lane) * 8;
#pragma unroll
  for (int ks = 0; ks < 8; ks++) {
    short8 a[MT];
#pragma unroll
    for (int mt = 0; mt < MT; mt++)
      a[mt] = *(const short8*)&As[(mt * 16 + m) * 264 + ks * 32 + q * 8];
#pragma unroll
    for (int nt = 0; nt < NTW; nt++) {
      short8 b = *(const short8*)(wbase + (size_t)(nt * 8 + ks) * 64 * 8);
#pragma unroll
      for (int mt = 0; mt < MT; mt++)
        acc[mt][nt] = __builtin_amdgcn_mfma_f32_16x16x32_bf16(a[mt], b, acc[mt][nt], 0, 0, 0);
    }
  }
  // Per-lane row->node mapping: rows mt*16+q*4+i; node = mt*2 + (q>>1).
  float mxa = 0.f, mxb = 0.f;
#pragma unroll
  for (int nt = 0; nt < NTW; nt++)
#pragma unroll
    for (int i = 0; i < 4; i++) {
      mxa = fmaxf(mxa, fabsf(acc[0][nt][i]));
      mxb = fmaxf(mxb, fabsf(acc[1][nt][i]));
    }
#pragma unroll
  for (int off = 16; off; off >>= 1) {
    mxa = fmaxf(mxa, __shfl_down(mxa, off));
    mxb = fmaxf(mxb, __shfl_down(mxb, off));
  }
  if (lane == 0)  { gmax[wv * 4 + 0] = mxa; gmax[wv * 4 + 2] = mxb; }
  if (lane == 32) { gmax[wv * 4 + 1] = mxa; gmax[wv * 4 + 3] = mxb; }
  __syncthreads();
  // global per-(node,half) scale
  if (tid < 4 * HALVES) {
    int node = (HALVES == 2) ? (tid >> 1) : tid;
    int half = (HALVES == 2) ? (tid & 1) : 0;
    float g = 0.f;
#pragma unroll
    for (int w = 0; w < WPG; w++) g = fmaxf(g, gmax[(half * WPG + w) * 4 + node]);
    float* sp = half ? sB : sA;
    sp[(rowBase >> 3) + node] = g * (1.0f / 127.0f);
  }
  // per-lane inverse scales for its two nodes
  int half = (HALVES == 2) ? (wv / WPG) : 0;
  int qh = q >> 1;
  float ga = 0.f, gb = 0.f;
#pragma unroll
  for (int w = 0; w < WPG; w++) {
    ga = fmaxf(ga, gmax[(half * WPG + w) * 4 + qh]);
    gb = fmaxf(gb, gmax[(half * WPG + w) * 4 + 2 + qh]);
  }
  float invA = (ga > 0.f) ? (127.0f / ga) : 0.f;
  float invB = (gb > 0.f) ? (127.0f / gb) : 0.f;
  // quantize acc directly -> byte stores (rows strided by 128B)
  signed char* qbase = (half ? qB : qA);
#pragma unroll
  for (int mt = 0; mt < MT; mt++) {
    float inv = mt ? invB : invA;
#pragma unroll
    for (int nt = 0; nt < NTW; nt++) {
      int colq = (wv * NTW + nt) * 16 + m - half * 128;
      signed char* dst = qbase + (size_t)(rowBase + mt * 16 + q * 4) * 128 + colq;
#pragma unroll
      for (int i = 0; i < 4; i++) {
        int qv = __float2int_rn(acc[mt][nt][i] * inv);
        dst[(size_t)i * 128] = (signed char)qv;
      }
    }
  }
}

// ---------------- bootstrap GEMM (stages both halves from global) ----------------

template <int NTW, int HALVES>
__global__ __launch_bounds__(512) void gemm_mfma_q(const unsigned short* __restrict__ A1,
                                                   const unsigned short* __restrict__ A2,
                                                   const unsigned short* __restrict__ Wp,
                                                   signed char* __restrict__ qA,
                                                   signed char* __restrict__ qB,
                                                   float* __restrict__ sA,
                                                   float* __restrict__ sB) {
  __shared__ unsigned short As[32 * 264];
  __shared__ float gmax[32];
  int rowBase = blockIdx.x * 32;
  int tid = threadIdx.x;
  for (int c = tid; c < 1024; c += 512) {
    int row = c >> 5; int rest = c & 31; int half = rest >> 4; int sub = rest & 15;
    const unsigned short* src = (half ? A2 : A1) + ((size_t)(rowBase + row) * 128 + sub * 8);
    *(uint4*)&As[row * 264 + half * 128 + sub * 8] = *(const uint4*)src;
  }
  __syncthreads();
  gemm_body<2, NTW, HALVES, 512>(As, gmax, Wp, qA, qB, sA, sB, rowBase, tid);
}

// ---------------- FUSED B/D: gates-gather prologue + candidate GEMM ----------------
// 8 gather units (4 nodes x {r,u}) -> one per wave. rh -> LDS A2; u -> global.
// A1 staged one-uint4-per-thread.

__global__ __launch_bounds__(512, 8) void fused_cand_q(
    const signed char* __restrict__ GqR, const signed char* __restrict__ GqU,
    const float* __restrict__ sR, const float* __restrict__ sU,
    const int* __restrict__ offs, const int* __restrict__ csr_src,
    const float* __restrict__ csr_w, const float* __restrict__ dis,
    const float* __restrict__ bRU, const unsigned short* __restrict__ h,
    unsigned short* __restrict__ u_out,
    const unsigned short* __restrict__ A1, const unsigned short* __restrict__ Wp,
    signed char* __restrict__ Cq, float* __restrict__ sC) {
  __shared__ unsigned short As[32 * 264];
  __shared__ float gmax[32];
  int tid = threadIdx.x;
  int wv = tid >> 6, lane = tid & 63;
  int rowBase = blockIdx.x * 32, gn0 = rowBase >> 3;
  int bb = lane >> 3, fo = (lane & 7) << 4;
  int node8 = wv >> 1, half = wv & 1;
  int n = gn0 + node8;
  int e0 = offs[n], e1 = offs[n + 1];   // metadata first (overlaps staging)
  // stage A1 (xin) into cols 0..127 — one uint4 per thread
  {
    int row = tid >> 4, sub = tid & 15;
    *(uint4*)&As[row * 264 + sub * 8] =
        *(const uint4*)&A1[(size_t)(rowBase + row) * 128 + sub * 8];
  }
  float acc[16];
  gather_accum(half ? GqU : GqR, half ? sU : sR, e0, e1, csr_src, csr_w, dis, n, bb, fo, acc);
  const float* bias = bRU + half * 128 + fo;
  size_t rowSelf = ((size_t)n << 3) + bb;
  if (half == 0) {
    int lr = node8 * 8 + bb;
#pragma unroll
    for (int jj = 0; jj < 2; jj++) {
      uint4 hq = *(const uint4*)&h[rowSelf * 128 + fo + 8 * jj];
      float hv[8];
      hv[0] = bflo(hq.x); hv[1] = bfhi(hq.x); hv[2] = bflo(hq.y); hv[3] = bfhi(hq.y);
      hv[4] = bflo(hq.z); hv[5] = bfhi(hq.z); hv[6] = bflo(hq.w); hv[7] = bfhi(hq.w);
      unsigned ow[4];
#pragma unroll
      for (int d = 0; d < 4; d++) {
        float s0 = 1.0f / (1.0f + __expf(-(acc[8 * jj + 2 * d]     + bias[8 * jj + 2 * d])));
        float s1 = 1.0f / (1.0f + __expf(-(acc[8 * jj + 2 * d + 1] + bias[8 * jj + 2 * d + 1])));
        ow[d] = (unsigned)f2bf(s0 * hv[2 * d]) | ((unsigned)f2bf(s1 * hv[2 * d + 1]) << 16);
      }
      uint4 o; o.x = ow[0]; o.y = ow[1]; o.z = ow[2]; o.w = ow[3];
      *(uint4*)&As[lr * 264 + 128 + fo + 8 * jj] = o;
    }
  } else {
#pragma unroll
    for (int jj = 0; jj < 2; jj++) {
      unsigned ow[4];
#pragma unroll
      for (int d = 0; d < 4; d++) {
        float s0 = 1.0f / (1.0f + __expf(-(acc[8 * jj + 2 * d]     + bias[8 * jj + 2 * d])));
        float s1 = 1.0f / (1.0f + __expf(-(acc[8 * jj + 2 * d + 1] + bias[8 * jj + 2 * d + 1])));
        ow[d] = (unsigned)f2bf(s0) | ((unsigned)f2bf(s1) << 16);
      }
      uint4 o; o.x = ow[0]; o.y = ow[1]; o.z = ow[2]; o.w = ow[3];
      *(uint4*)&u_out[rowSelf * 128 + fo + 8 * jj] = o;
    }
  }
  __syncthreads();
  gemm_body<2, 1, 1, 512>(As, gmax, Wp, Cq, Cq, sC, sC, rowBase, tid);
}

// ---------------- FUSED C: cand-gather + GRU prologue + gates GEMM ----------------
// Waves 0-3: full-degree cand-gather node wv, GRU (u from global) -> h + LDS A1.
// Waves 4-7: stage A2 (other layer's state).

__global__ __launch_bounds__(512, 8) void fused_gates_q(
    const signed char* __restrict__ Cq, const float* __restrict__ sC,
    const int* __restrict__ offs, const int* __restrict__ csr_src,
    const float* __restrict__ csr_w, const float* __restrict__ dis,
    const float* __restrict__ bC, const unsigned short* __restrict__ u_in,
    unsigned short* __restrict__ h_io,
    const unsigned short* __restrict__ A2src, const unsigned short* __restrict__ Wp,
    signed char* __restrict__ GqRo, signed char* __restrict__ GqUo,
    float* __restrict__ sRo, float* __restrict__ sUo) {
  __shared__ unsigned short As[32 * 264];
  __shared__ float gmax[32];
  int tid = threadIdx.x;
  int wv = tid >> 6, lane = tid & 63;
  int rowBase = blockIdx.x * 32, gn0 = rowBase >> 3;
  int bb = lane >> 3, fo = (lane & 7) << 4;
  if (wv >= 4) {
    int t2 = tid - 256;
    for (int c = t2; c < 512; c += 256) {
      int row = c >> 4, sub = c & 15;
      *(uint4*)&As[row * 264 + 128 + sub * 8] =
          *(const uint4*)&A2src[(size_t)(rowBase + row) * 128 + sub * 8];
    }
  } else {
    int node8 = wv;
    int n = gn0 + node8;
    int e0 = offs[n], e1 = offs[n + 1];
    float acc[16];
    gather_accum(Cq, sC, e0, e1, csr_src, csr_w, dis, n, bb, fo, acc);
    size_t rowSelf = ((size_t)n << 3) + bb;
    uint4 o0, o1;
    gru_combine_store(acc, bC + fo, u_in, h_io, rowSelf, fo, o0, o1);
    int lr = node8 * 8 + bb;
    *(uint4*)&As[lr * 264 + fo] = o0;
    *(uint4*)&As[lr * 264 + fo + 8] = o1;
  }
  __syncthreads();
  gemm_body<2, 2, 2, 512>(As, gmax, Wp, GqRo, GqUo, sRo, sUo, rowBase, tid);
}

// ---------------- FUSED E: cand-gather h1 GRU + lin_in(t+1) + gates0 GEMM ----------
// Waves 0-3: cand-gather node wv, GRU (u from global) -> h1 global.
// Waves 4-7: stage A2 (h0) + lin_in(t+1) -> LDS A1 + global xt.

__global__ __launch_bounds__(512, 8) void fused_gates_lin_q(
    const signed char* __restrict__ Cq, const float* __restrict__ sC,
    const int* __restrict__ offs, const int* __restrict__ csr_src,
    const float* __restrict__ csr_w, const float* __restrict__ dis,
    const float* __restrict__ bC, const unsigned short* __restrict__ u_in,
    unsigned short* __restrict__ h_io,
    const float* __restrict__ x_seq, const float* __restrict__ Win,
    const float* __restrict__ bin, unsigned short* __restrict__ xt_out,
    const unsigned short* __restrict__ A2src, const unsigned short* __restrict__ Wp,
    signed char* __restrict__ GqRo, signed char* __restrict__ GqUo,
    float* __restrict__ sRo, float* __restrict__ sUo, int t_next) {
  __shared__ unsigned short As[32 * 264];
  __shared__ float gmax[32];
  int tid = threadIdx.x;
  int wv = tid >> 6, lane = tid & 63;
  int rowBase = blockIdx.x * 32, gn0 = rowBase >> 3;
  int bb = lane >> 3, fo = (lane & 7) << 4;
  if (wv < 4) {
    int node8 = wv;
    int n = gn0 + node8;
    int e0 = offs[n], e1 = offs[n + 1];
    float acc[16];
    gather_accum(Cq, sC, e0, e1, csr_src, csr_w, dis, n, bb, fo, acc);
    size_t rowSelf = ((size_t)n << 3) + bb;
    uint4 o0, o1;
    gru_combine_store(acc, bC + fo, u_in, h_io, rowSelf, fo, o0, o1);
  } else {
    int t2 = tid - 256;
    // stage A2 (h0) into cols 128..255
    for (int c = t2; c < 512; c += 256) {
      int row = c >> 4, sub = c & 15;
      *(uint4*)&As[row * 264 + 128 + sub * 8] =
          *(const uint4*)&A2src[(size_t)(rowBase + row) * 128 + sub * 8];
    }
    // lin_in for t_next: 32 rows x 16 fh-units -> LDS cols 0..127 + global xt
    for (int c = t2; c < 512; c += 256) {
      int row = c >> 4, fh = c & 15;
      int grow = rowBase + row;
      int n2 = grow >> 3, bbv = grow & 7;
      const float* xp = x_seq + (((size_t)bbv * SS + t_next) * NN + n2) * FF;
      float4 a0 = *(const float4*)&bin[fh * 8];
      float4 a1 = *(const float4*)&bin[fh * 8 + 4];
#pragma unroll
      for (int ff = 0; ff < FF; ff++) {
        float xv = xp[ff];
        float4 w0 = *(const float4*)&Win[ff * HH + fh * 8];
        float4 w1 = *(const float4*)&Win[ff * HH + fh * 8 + 4];
        a0.x += xv * w0.x; a0.y += xv * w0.y; a0.z += xv * w0.z; a0.w += xv * w0.w;
        a1.x += xv * w1.x; a1.y += xv * w1.y; a1.z += xv * w1.z; a1.w += xv * w1.w;
      }
      uint4 o;
      o.x = (unsigned)f2bf(fmaxf(a0.x, 0.f)) | ((unsigned)f2bf(fmaxf(a0.y, 0.f)) << 16);
      o.y = (unsigned)f2bf(fmaxf(a0.z, 0.f)) | ((unsigned)f2bf(fmaxf(a0.w, 0.f)) << 16);
      o.z = (unsigned)f2bf(fmaxf(a1.x, 0.f)) | ((unsigned)f2bf(fmaxf(a1.y, 0.f)) << 16);
      o.w = (unsigned)f2bf(fmaxf(a1.z, 0.f)) | ((unsigned)f2bf(fmaxf(a1.w, 0.f)) << 16);
      *(uint4*)&As[row * 264 + fh * 8] = o;
      *(uint4*)&xt_out[(size_t)grow * 128 + fh * 8] = o;
    }
  }
  __syncthreads();
  gemm_body<2, 2, 2, 512>(As, gmax, Wp, GqRo, GqUo, sRo, sUo, rowBase, tid);
}

// ---------------- final candidate aggregation + GRU update (t = S-1, layer 1) --------

__global__ __launch_bounds__(256) void scatter_c_update_q(
    const signed char* __restrict__ Cq, const float* __restrict__ sC,
    const int* __restrict__ offs, const int* __restrict__ csr_src,
    const float* __restrict__ csr_w, const float* __restrict__ dis,
    const float* __restrict__ bC, const unsigned short* __restrict__ u,
    unsigned short* __restrict__ h) {
  int tid = threadIdx.x;
  int wv = tid >> 6, lane = tid & 63;
  int n = blockIdx.x * 4 + wv;
  int bb = lane >> 3;
  int fo = (lane & 7) << 4;
  int e0 = offs[n], e1 = offs[n + 1];
  float acc[16];
  gather_accum(Cq, sC, e0, e1, csr_src, csr_w, dis, n, bb, fo, acc);
  size_t rowSelf = (size_t)(n << 3) + bb;
  uint4 o0, o1;
  gru_combine_store(acc, bC + fo, u, h, rowSelf, fo, o0, o1);
}

// ---------------- BatchNorm stats ----------------

__global__ __launch_bounds__(256) void bn_stats_kernel(const unsigned short* __restrict__ h,
                                                       float* __restrict__ sums) {
  __shared__ float ls[512];
  int tid = threadIdx.x;
  float s = 0.f, sq = 0.f;
  for (size_t idx = (size_t)blockIdx.x * 256 + tid; idx < (size_t)TOTAL * HH;
       idx += (size_t)gridDim.x * 256) {
    float v = bf2f(h[idx]);
    s += v; sq += v * v;
  }
  ls[tid] = s; ls[256 + tid] = sq;
  __syncthreads();
  if (tid < 128) {
    atomicAdd(&sums[tid], ls[tid] + ls[tid + 128]);
    atomicAdd(&sums[128 + tid], ls[256 + tid] + ls[256 + tid + 128]);
  }
}

// ---------------- fused BN -> relu -> lin_out -> log_softmax ----------------

__global__ __launch_bounds__(256) void final_kernel(const unsigned short* __restrict__ h,
                                                    const float* __restrict__ sums,
                                                    const float* __restrict__ gamma,
                                                    const float* __restrict__ beta,
                                                    const float* __restrict__ Wout,
                                                    const float* __restrict__ bout,
                                                    float* __restrict__ out) {
  int wid = threadIdx.x >> 6, lane = threadIdx.x & 63;
  int row = blockIdx.x * 4 + wid; // node-row (n*8+bb order)
  if (row >= TOTAL) return;
  const float inv = 1.0f / (float)TOTAL;
  float p0 = 0.f, p1 = 0.f, p2 = 0.f, p3 = 0.f;
#pragma unroll
  for (int jj = 0; jj < 2; jj++) {
    int j = lane + jj * 64;
    float mean = sums[j] * inv;
    float var = sums[128 + j] * inv - mean * mean;
    float hn = (bf2f(h[(size_t)row * HH + j]) - mean) * rsqrtf(var + 1e-5f) * gamma[j] + beta[j];
    hn = fmaxf(hn, 0.0f);
    p0 += hn * Wout[j * 4 + 0];
    p1 += hn * Wout[j * 4 + 1];
    p2 += hn * Wout[j * 4 + 2];
    p3 += hn * Wout[j * 4 + 3];
  }
  for (int off = 32; off; off >>= 1) {
    p0 += __shfl_down(p0, off);
    p1 += __shfl_down(p1, off);
    p2 += __shfl_down(p2, off);
    p3 += __shfl_down(p3, off);
  }
  if (lane == 0) {
    p0 += bout[0]; p1 += bout[1]; p2 += bout[2]; p3 += bout[3];
    float m = fmaxf(fmaxf(p0, p1), fmaxf(p2, p3));
    float e = __expf(p0 - m) + __expf(p1 - m) + __expf(p2 - m) + __expf(p3 - m);
    float lse = m + __logf(e);
    int bb = row & 7, n = row >> 3;
    float* o = out + ((size_t)bb * NN + n) * 4;
    o[0] = p0 - lse; o[1] = p1 - lse; o[2] = p2 - lse; o[3] = p3 - lse;
  }
}

// ---------------- launcher ----------------

extern "C" void kernel_launch(void* const* d_in, const int* in_sizes, int n_in,
                              void* d_out, int out_size, void* d_ws, size_t ws_size,
                              hipStream_t stream) {
  const float* x_seq = (const float*)d_in[0];
  const int* ei      = (const int*)d_in[1];
  const float* ew    = (const float*)d_in[2];
  const float* Win   = (const float*)d_in[3];
  const float* bin   = (const float*)d_in[4];
  const float* convW = (const float*)d_in[5];
  const float* convB = (const float*)d_in[6];
  const float* gamma = (const float*)d_in[7];
  const float* beta  = (const float*)d_in[8];
  const float* Wout  = (const float*)d_in[9];
  const float* bout  = (const float*)d_in[10];
  float* out = (float*)d_out;

  char* ws = (char*)d_ws;
  size_t off = 0;
  auto alloc = [&](size_t bytes) {
    void* p = ws + off;
    off += (bytes + 1023) & ~(size_t)1023;
    return p;
  };
  float* deg     = (float*)alloc(NN * 4);
  float* dis     = (float*)alloc(NN * 4);
  int*   cnt     = (int*)alloc(NN * 4);
  int*   offs    = (int*)alloc((NN + 1) * 4);
  int*   cursor  = (int*)alloc(NN * 4);
  int*   csr_src = (int*)alloc(EE * 4);
  float* csr_w   = (float*)alloc(EE * 4);
  float* sums    = (float*)alloc(256 * 4);
  float* sR      = (float*)alloc(NN * 4);
  float* sU      = (float*)alloc(NN * 4);
  float* sC      = (float*)alloc(NN * 4);
  unsigned short* Wp = (unsigned short*)alloc(6 * 32768 * 2);  // packed conv weights
  const size_t NH = (size_t)TOTAL * HH; // 5,120,000
  unsigned short* h0 = (unsigned short*)alloc(NH * 2);
  unsigned short* h1 = (unsigned short*)alloc(NH * 2);
  unsigned short* xt = (unsigned short*)alloc(NH * 2);
  unsigned short* ub = (unsigned short*)alloc(NH * 2);
  signed char* GqR = (signed char*)alloc(NH);   // int8 messages
  signed char* GqU = (signed char*)alloc(NH);
  signed char* Cq  = (signed char*)alloc(NH);   // DEDICATED (no alias with GqR!)

  hipMemsetAsync(deg, 0, NN * 4, stream);
  hipMemsetAsync(cnt, 0, NN * 4, stream);
  hipMemsetAsync(cursor, 0, NN * 4, stream);
  hipMemsetAsync(sums, 0, 256 * 4, stream);
  hipMemsetAsync(h0, 0, NH * 2, stream);
  hipMemsetAsync(h1, 0, NH * 2, stream);

  deg_cnt_kernel<<<(EE + 255) / 256, 256, 0, stream>>>(ei, ew, deg, cnt);
  dis_kernel<<<(NN + 255) / 256, 256, 0, stream>>>(deg, dis);
  scan_kernel<<<1, 256, 0, stream>>>(cnt, offs);
  fill_csr_kernel<<<(EE + 255) / 256, 256, 0, stream>>>(ei, ew, dis, offs, cursor, csr_src, csr_w);
  prepack_kernel<<<24576 / 256, 256, 0, stream>>>(convW, Wp);

  const unsigned short* Wg0 = Wp;
  const unsigned short* Wc0 = Wp + (size_t)2 * 32768;
  const unsigned short* Wg1 = Wp + (size_t)3 * 32768;
  const unsigned short* Wc1 = Wp + (size_t)5 * 32768;
  const float* bRU0 = convB;
  const float* bC0  = convB + 2 * HH;
  const float* bRU1 = convB + 3 * HH;
  const float* bC1  = convB + 5 * HH;

  // bootstrap: xt(t=0), gates0(t=0)
  lin_in_kernel<<<TOTAL * 16 / 256, 256, 0, stream>>>(x_seq, Win, bin, xt, 0);
  gemm_mfma_q<2, 2><<<TOTAL / 32, 512, 0, stream>>>(xt, h0, Wg0, GqR, GqU, sR, sU);

  for (int t = 0; t < SS; t++) {
    // B: gates0-gather -> rh0(LDS), u0 -> cand0 GEMM -> Cq
    fused_cand_q<<<TOTAL / 32, 512, 0, stream>>>(GqR, GqU, sR, sU, offs, csr_src, csr_w,
                                                 dis, bRU0, h0, ub, xt, Wc0, Cq, sC);
    // C: cand0-gather -> h0 update (global+LDS A1) -> gates1 GEMM -> GqR/GqU
    fused_gates_q<<<TOTAL / 32, 512, 0, stream>>>(Cq, sC, offs, csr_src, csr_w, dis,
                                                  bC0, ub, h0, h1, Wg1, GqR, GqU, sR, sU);
    // D: gates1-gather -> rh1(LDS), u1 -> cand1 GEMM -> Cq
    fused_cand_q<<<TOTAL / 32, 512, 0, stream>>>(GqR, GqU, sR, sU, offs, csr_src, csr_w,
                                                 dis, bRU1, h1, ub, h0, Wc1, Cq, sC);
    // E: cand1-gather -> h1 update; lin_in(t+1) -> xt; gates0 GEMM -> GqR/GqU
    if (t < SS - 1) {
      fused_gates_lin_q<<<TOTAL / 32, 512, 0, stream>>>(Cq, sC, offs, csr_src, csr_w, dis,
                                                        bC1, ub, h1, x_seq, Win, bin, xt,
                                                        h0, Wg0, GqR, GqU, sR, sU, t + 1);
    } else {
      scatter_c_update_q<<<NN / 4, 256, 0, stream>>>(Cq, sC, offs, csr_src, csr_w,
                                                     dis, bC1, ub, h1);
    }
  }

  bn_stats_kernel<<<256, 256, 0, stream>>>(h1, sums);
  final_kernel<<<TOTAL / 4, 256, 0, stream>>>(h1, sums, gamma, beta, Wout, bout, out);
}

// Round 9
// 1521.300 us; speedup vs baseline: 1.0739x; 1.0237x over previous
//
#include <hip/hip_runtime.h>
#include <cstdint>
#include <cstddef>

#define NN 5000     // nodes per batch block
#define EE 40000    // edges per batch block
#define BATCH 8
#define SS 12
#define FF 16
#define HH 128
#define TOTAL 40000 // BATCH*NN
#define CC 4

// Layout: per-row state arrays use row = n*8 + bb (batch-interleaved). Gather-only
// message matrices are INT8 with one fp32 scale per source node per matrix.
//
// Fused schedule (R5/R7 structure): B cand0-GEMM, C gates1-GEMM, D cand1-GEMM,
// E gates0-GEMM(+lin_in t+1); each kernel's PROLOGUE gathers the previous
// GEMM's messages for its own 4 nodes. 32-row tiles, 512 threads, 4 blk/CU.
//
// R8 (resubmitted R9 — prior round was an infra failure, kernel never ran):
// LANE-PARALLEL GATHER METADATA. One coalesced load fetches all <=64 edge
// indices+weights (lane l <- e0+l) plus per-source scales sc[idx] lane-parallel;
// per-edge values broadcast via __shfl (readlane). All Gq 1KB row loads then
// issue mutually independent -> dependent memory levels 4 -> 2 in the prologue
// critical path. (R7 proved epilogue VALU wasn't critical; R6 proved extra
// random FETCH hurts; R4 proved edge-splitting without MLP gain hurts.)
//
// CORRECTNESS (G16): Cq dedicated (not aliasing GqR) — cross-block race at
// grid > co-residency, proven in R2.

typedef __attribute__((ext_vector_type(8))) short short8;   // 8 bf16 (4 VGPRs)
typedef __attribute__((ext_vector_type(4))) float f32x4;    // 4 fp32

__device__ __forceinline__ unsigned short f2bf(float f) {
  union { float f; unsigned u; } v; v.f = f;
  unsigned r = v.u + 0x7fff + ((v.u >> 16) & 1);  // RTNE
  return (unsigned short)(r >> 16);
}
__device__ __forceinline__ float bf2f(unsigned short b) {
  union { unsigned u; float f; } v; v.u = ((unsigned)b) << 16;
  return v.f;
}
__device__ __forceinline__ float bflo(unsigned v) {
  union { unsigned u; float f; } x; x.u = v << 16; return x.f;
}
__device__ __forceinline__ float bfhi(unsigned v) {
  union { unsigned u; float f; } x; x.u = v & 0xffff0000u; return x.f;
}
// acc[0..15] += ws * (int8x16 from qv)
__device__ __forceinline__ void qfma16(float* acc, uint4 qv, float ws) {
  unsigned wd[4] = {qv.x, qv.y, qv.z, qv.w};
#pragma unroll
  for (int d = 0; d < 4; d++) {
#pragma unroll
    for (int k = 0; k < 4; k++) {
      int q = (int)((signed char)(wd[d] >> (8 * k)));
      acc[d * 4 + k] += ws * (float)q;
    }
  }
}

// Full-degree gather: one wave owns one (node, matrix) unit.
// lane -> (bb = lane>>3, 16 feats at (lane&7)*16). acc[16] out.
// Lane-parallel metadata: lane l loads csr_src/csr_w[e0+l] and sc[idx] in ONE
// round; per-edge broadcast via __shfl; Gq row loads all independent.
__device__ __forceinline__ void gather_accum(const signed char* __restrict__ Gq,
                                             const float* __restrict__ sc,
                                             int e0, int e1,
                                             const int* __restrict__ csr_src,
                                             const float* __restrict__ csr_w,
                                             const float* __restrict__ dis,
                                             int n, int bb, int fo, float* acc) {
  int lane = (bb << 3) | (fo >> 4);
  int deg = e1 - e0;
  int myi = 0; float myw = 0.f;
  if (lane < deg) {
    myi = csr_src[e0 + lane];
    myw = csr_w[e0 + lane];
  }
  float mys = sc[myi];                 // lane-parallel scale gather (idx 0 if idle)
  float sn = dis[n]; sn *= sn;
  size_t rowSelf = (size_t)(n << 3) + bb;
#pragma unroll
  for (int k = 0; k < 16; k++) acc[k] = 0.f;
  {
    float ws = sn * sc[n];
    uint4 qv = *(const uint4*)&Gq[rowSelf * 128 + fo];
    qfma16(acc, qv, ws);
  }
  int dmax = deg < 64 ? deg : 64;
  int e = 0;
  for (; e + 3 < dmax; e += 4) {
    int s0 = __shfl(myi, e),     s1 = __shfl(myi, e + 1);
    int s2 = __shfl(myi, e + 2), s3 = __shfl(myi, e + 3);
    uint4 qa = *(const uint4*)&Gq[(((size_t)s0 << 3) + bb) * 128 + fo];
    uint4 qb = *(const uint4*)&Gq[(((size_t)s1 << 3) + bb) * 128 + fo];
    uint4 qc = *(const uint4*)&Gq[(((size_t)s2 << 3) + bb) * 128 + fo];
    uint4 qd = *(const uint4*)&Gq[(((size_t)s3 << 3) + bb) * 128 + fo];
    float w0 = __shfl(myw, e)     * __shfl(mys, e);
    float w1 = __shfl(myw, e + 1) * __shfl(mys, e + 1);
    float w2 = __shfl(myw, e + 2) * __shfl(mys, e + 2);
    float w3 = __shfl(myw, e + 3) * __shfl(mys, e + 3);
    qfma16(acc, qa, w0);
    qfma16(acc, qb, w1);
    qfma16(acc, qc, w2);
    qfma16(acc, qd, w3);
  }
  for (; e < dmax; e++) {
    int s0 = __shfl(myi, e);
    float w0 = __shfl(myw, e) * __shfl(mys, e);
    uint4 qa = *(const uint4*)&Gq[(((size_t)s0 << 3) + bb) * 128 + fo];
    qfma16(acc, qa, w0);
  }
  // rare tail: deg > 64 (scalar path, keeps correctness for any graph)
  for (int ee = e0 + 64; ee < e1; ee++) {
    int s0 = csr_src[ee];
    float w0 = csr_w[ee] * sc[s0];
    uint4 qa = *(const uint4*)&Gq[(((size_t)s0 << 3) + bb) * 128 + fo];
    qfma16(acc, qa, w0);
  }
}

// GRU combine, 8-element chunks (low register pressure), u from global bf16:
// h_new = u*h + (1-u)*tanh(acc+b); writes h back to global; o0/o1 packed rows.
__device__ __forceinline__ void gru_combine_store(const float* acc, const float* bp,
                                                  const unsigned short* __restrict__ u_in,
                                                  unsigned short* __restrict__ h_io,
                                                  size_t rowSelf, int fo,
                                                  uint4& o0, uint4& o1) {
  uint4 oo[2];
#pragma unroll
  for (int jj = 0; jj < 2; jj++) {
    uint4 uq = *(const uint4*)&u_in[rowSelf * 128 + fo + 8 * jj];
    uint4 hq = *(const uint4*)&h_io[rowSelf * 128 + fo + 8 * jj];
    float uv[8], hv[8];
    uv[0] = bflo(uq.x); uv[1] = bfhi(uq.x); uv[2] = bflo(uq.y); uv[3] = bfhi(uq.y);
    uv[4] = bflo(uq.z); uv[5] = bfhi(uq.z); uv[6] = bflo(uq.w); uv[7] = bfhi(uq.w);
    hv[0] = bflo(hq.x); hv[1] = bfhi(hq.x); hv[2] = bflo(hq.y); hv[3] = bfhi(hq.y);
    hv[4] = bflo(hq.z); hv[5] = bfhi(hq.z); hv[6] = bflo(hq.w); hv[7] = bfhi(hq.w);
    unsigned ow[4];
#pragma unroll
    for (int d = 0; d < 4; d++) {
      float v0 = acc[8 * jj + 2 * d]     + bp[8 * jj + 2 * d];
      float v1 = acc[8 * jj + 2 * d + 1] + bp[8 * jj + 2 * d + 1];
      float c0 = 1.0f - 2.0f / (__expf(2.0f * v0) + 1.0f);  // tanh
      float c1 = 1.0f - 2.0f / (__expf(2.0f * v1) + 1.0f);
      float n0 = uv[2 * d] * hv[2 * d] + (1.0f - uv[2 * d]) * c0;
      float n1 = uv[2 * d + 1] * hv[2 * d + 1] + (1.0f - uv[2 * d + 1]) * c1;
      ow[d] = (unsigned)f2bf(n0) | ((unsigned)f2bf(n1) << 16);
    }
    oo[jj].x = ow[0]; oo[jj].y = ow[1]; oo[jj].z = ow[2]; oo[jj].w = ow[3];
    *(uint4*)&h_io[rowSelf * 128 + fo + 8 * jj] = oo[jj];
  }
  o0 = oo[0]; o1 = oo[1];
}

// ---------------- graph preprocessing (once per launch) ----------------

__global__ void deg_cnt_kernel(const int* __restrict__ ei, const float* __restrict__ ew,
                               float* __restrict__ deg, int* __restrict__ cnt) {
  int e = blockIdx.x * 256 + threadIdx.x;
  if (e < EE) {
    int col = ei[EE + e];
    atomicAdd(&deg[col], ew[e]);
    atomicAdd(&cnt[col], 1);
  }
}

__global__ void dis_kernel(const float* __restrict__ deg, float* __restrict__ dis) {
  int n = blockIdx.x * 256 + threadIdx.x;
  if (n < NN) dis[n] = rsqrtf(deg[n] + 1.0f);  // +1: self-loop weight
}

__global__ void scan_kernel(const int* __restrict__ cnt, int* __restrict__ offs) {
  __shared__ int part[256];
  const int CH = (NN + 255) / 256; // 20
  int tid = threadIdx.x;
  int base = tid * CH;
  int s = 0;
  for (int i = 0; i < CH; i++) { int idx = base + i; if (idx < NN) s += cnt[idx]; }
  part[tid] = s;
  __syncthreads();
  for (int off = 1; off < 256; off <<= 1) {
    int v = (tid >= off) ? part[tid - off] : 0;
    __syncthreads();
    part[tid] += v;
    __syncthreads();
  }
  int run = (tid == 0) ? 0 : part[tid - 1];
  for (int i = 0; i < CH; i++) {
    int idx = base + i;
    if (idx < NN) { offs[idx] = run; run += cnt[idx]; }
  }
  if (tid == 255) offs[NN] = run;
}

__global__ void fill_csr_kernel(const int* __restrict__ ei, const float* __restrict__ ew,
                                const float* __restrict__ dis, const int* __restrict__ offs,
                                int* __restrict__ cursor, int* __restrict__ csr_src,
                                float* __restrict__ csr_w) {
  int e = blockIdx.x * 256 + threadIdx.x;
  if (e < EE) {
    int row = ei[e], col = ei[EE + e];
    int pos = offs[col] + atomicAdd(&cursor[col], 1);
    csr_src[pos] = row;
    csr_w[pos] = dis[row] * ew[e] * dis[col];
  }
}

// ---------------- weight prepack: fp32 [k][n] -> bf16 MFMA b-frag order ----------------

__global__ void prepack_kernel(const float* __restrict__ convW, unsigned short* __restrict__ Wp) {
  int idx = blockIdx.x * 256 + threadIdx.x;  // 6*8*8*64 = 24576
  int lane = idx & 63;
  int ks = (idx >> 6) & 7;
  int nt = (idx >> 9) & 7;
  int g = idx >> 12;
  const float* W = convW + (size_t)g * 256 * 128;
  int n = nt * 16 + (lane & 15);
  int k0 = ks * 32 + (lane >> 4) * 8;
  unsigned short v[8];
#pragma unroll
  for (int j = 0; j < 8; j++) v[j] = f2bf(W[(size_t)(k0 + j) * 128 + n]);
  *(uint4*)(Wp + (size_t)idx * 8) = *(const uint4*)v;
}

// ---------------- lin_in (bootstrap t=0 only) ----------------

__global__ __launch_bounds__(256) void lin_in_kernel(const float* __restrict__ x_seq,
                                                     const float* __restrict__ W,
                                                     const float* __restrict__ b,
                                                     unsigned short* __restrict__ xt, int t) {
  int idx = blockIdx.x * 256 + threadIdx.x;   // over TOTAL*16
  int row = idx >> 4, fh = idx & 15;          // feats 8fh..8fh+7
  int n = row >> 3, bb = row & 7;
  const float* xp = x_seq + (((size_t)bb * SS + t) * NN + n) * FF;
  float4 a0 = *(const float4*)&b[fh * 8];
  float4 a1 = *(const float4*)&b[fh * 8 + 4];
#pragma unroll
  for (int ff = 0; ff < FF; ff++) {
    float xv = xp[ff];
    float4 w0 = *(const float4*)&W[ff * HH + fh * 8];
    float4 w1 = *(const float4*)&W[ff * HH + fh * 8 + 4];
    a0.x += xv * w0.x; a0.y += xv * w0.y; a0.z += xv * w0.z; a0.w += xv * w0.w;
    a1.x += xv * w1.x; a1.y += xv * w1.y; a1.z += xv * w1.z; a1.w += xv * w1.w;
  }
  uint4 o;
  o.x = (unsigned)f2bf(fmaxf(a0.x, 0.f)) | ((unsigned)f2bf(fmaxf(a0.y, 0.f)) << 16);
  o.y = (unsigned)f2bf(fmaxf(a0.z, 0.f)) | ((unsigned)f2bf(fmaxf(a0.w, 0.f)) << 16);
  o.z = (unsigned)f2bf(fmaxf(a1.x, 0.f)) | ((unsigned)f2bf(fmaxf(a1.y, 0.f)) << 16);
  o.w = (unsigned)f2bf(fmaxf(a1.z, 0.f)) | ((unsigned)f2bf(fmaxf(a1.w, 0.f)) << 16);
  *(uint4*)&xt[(size_t)row * 128 + fh * 8] = o;
}

// ---------------- shared GEMM body (32-row tile, 8 waves) ----------------
// As (32 x 256 bf16, stride 264) staged by caller (caller syncs). MFMA, then
// per-(node,half) absmax computed FROM ACCUMULATORS (shfl + gmax LDS reduce),
// then int8 quantize acc directly -> byte stores to global. gmax = float[32].

template <int MT, int NTW, int HALVES, int NTHREADS>
__device__ __forceinline__ void gemm_body(const unsigned short* As, float* gmax,
                                          const unsigned short* __restrict__ Wp,
                                          signed char* __restrict__ qA,
                                          signed char* __restrict__ qB,
                                          float* __restrict__ sA,
                                          float* __restrict__ sB,
                                          int rowBase, int tid) {
  constexpr int NWAVES = NTHREADS / 64;     // 8
  constexpr int WPG = NWAVES / HALVES;      // waves per half: 4 or 8
  static_assert(MT == 2, "node mapping assumes 32-row tile");
  int wv = tid >> 6, lane = tid & 63;
  int m = lane & 15, q = lane >> 4;
  f32x4 acc[MT][NTW];
#pragma unroll
  for (int i = 0; i < MT; i++)
#pragma unroll
    for (int j = 0; j < NTW; j++) acc[i][j] = (f32x4)(0.0f);
  const unsigned short* wbase = Wp + ((size_t)(wv * NTW) * 8 * 64 + lane) * 8;
#pragma unroll
  for (int ks = 0; ks < 8; ks++) {
    short8 a[MT];
#pragma unroll
    for (int mt = 0; mt < MT; mt++)
      a[mt] = *(const short8*)&As[(mt * 16 + m) * 264 + ks * 32 + q * 8];
#pragma unroll
    for (int nt = 0; nt < NTW; nt++) {
      short8 b = *(const short8*)(wbase + (size_t)(nt * 8 + ks) * 64 * 8);
#pragma unroll
      for (int mt = 0; mt < MT; mt++)
        acc[mt][nt] = __builtin_amdgcn_mfma_f32_16x16x32_bf16(a[mt], b, acc[mt][nt], 0, 0, 0);
    }
  }
  // Per-lane row->node mapping: rows mt*16+q*4+i; node = mt*2 + (q>>1).
  float mxa = 0.f, mxb = 0.f;
#pragma unroll
  for (int nt = 0; nt < NTW; nt++)
#pragma unroll
    for (int i = 0; i < 4; i++) {
      mxa = fmaxf(mxa, fabsf(acc[0][nt][i]));
      mxb = fmaxf(mxb, fabsf(acc[1][nt][i]));
    }
#pragma unroll
  for (int off = 16; off; off >>= 1) {
    mxa = fmaxf(mxa, __shfl_down(mxa, off));
    mxb = fmaxf(mxb, __shfl_down(mxb, off));
  }
  if (lane == 0)  { gmax[wv * 4 + 0] = mxa; gmax[wv * 4 + 2] = mxb; }
  if (lane == 32) { gmax[wv * 4 + 1] = mxa; gmax[wv * 4 + 3] = mxb; }
  __syncthreads();
  // global per-(node,half) scale
  if (tid < 4 * HALVES) {
    int node = (HALVES == 2) ? (tid >> 1) : tid;
    int half = (HALVES == 2) ? (tid & 1) : 0;
    float g = 0.f;
#pragma unroll
    for (int w = 0; w < WPG; w++) g = fmaxf(g, gmax[(half * WPG + w) * 4 + node]);
    float* sp = half ? sB : sA;
    sp[(rowBase >> 3) + node] = g * (1.0f / 127.0f);
  }
  // per-lane inverse scales for its two nodes
  int half = (HALVES == 2) ? (wv / WPG) : 0;
  int qh = q >> 1;
  float ga = 0.f, gb = 0.f;
#pragma unroll
  for (int w = 0; w < WPG; w++) {
    ga = fmaxf(ga, gmax[(half * WPG + w) * 4 + qh]);
    gb = fmaxf(gb, gmax[(half * WPG + w) * 4 + 2 + qh]);
  }
  float invA = (ga > 0.f) ? (127.0f / ga) : 0.f;
  float invB = (gb > 0.f) ? (127.0f / gb) : 0.f;
  // quantize acc directly -> byte stores (rows strided by 128B)
  signed char* qbase = (half ? qB : qA);
#pragma unroll
  for (int mt = 0; mt < MT; mt++) {
    float inv = mt ? invB : invA;
#pragma unroll
    for (int nt = 0; nt < NTW; nt++) {
      int colq = (wv * NTW + nt) * 16 + m - half * 128;
      signed char* dst = qbase + (size_t)(rowBase + mt * 16 + q * 4) * 128 + colq;
#pragma unroll
      for (int i = 0; i < 4; i++) {
        int qv = __float2int_rn(acc[mt][nt][i] * inv);
        dst[(size_t)i * 128] = (signed char)qv;
      }
    }
  }
}

// ---------------- bootstrap GEMM (stages both halves from global) ----------------

template <int NTW, int HALVES>
__global__ __launch_bounds__(512) void gemm_mfma_q(const unsigned short* __restrict__ A1,
                                                   const unsigned short* __restrict__ A2,
                                                   const unsigned short* __restrict__ Wp,
                                                   signed char* __restrict__ qA,
                                                   signed char* __restrict__ qB,
                                                   float* __restrict__ sA,
                                                   float* __restrict__ sB) {
  __shared__ unsigned short As[32 * 264];
  __shared__ float gmax[32];
  int rowBase = blockIdx.x * 32;
  int tid = threadIdx.x;
  for (int c = tid; c < 1024; c += 512) {
    int row = c >> 5; int rest = c & 31; int half = rest >> 4; int sub = rest & 15;
    const unsigned short* src = (half ? A2 : A1) + ((size_t)(rowBase + row) * 128 + sub * 8);
    *(uint4*)&As[row * 264 + half * 128 + sub * 8] = *(const uint4*)src;
  }
  __syncthreads();
  gemm_body<2, NTW, HALVES, 512>(As, gmax, Wp, qA, qB, sA, sB, rowBase, tid);
}

// ---------------- FUSED B/D: gates-gather prologue + candidate GEMM ----------------
// 8 gather units (4 nodes x {r,u}) -> one per wave. rh -> LDS A2; u -> global.
// A1 staged one-uint4-per-thread.

__global__ __launch_bounds__(512, 8) void fused_cand_q(
    const signed char* __restrict__ GqR, const signed char* __restrict__ GqU,
    const float* __restrict__ sR, const float* __restrict__ sU,
    const int* __restrict__ offs, const int* __restrict__ csr_src,
    const float* __restrict__ csr_w, const float* __restrict__ dis,
    const float* __restrict__ bRU, const unsigned short* __restrict__ h,
    unsigned short* __restrict__ u_out,
    const unsigned short* __restrict__ A1, const unsigned short* __restrict__ Wp,
    signed char* __restrict__ Cq, float* __restrict__ sC) {
  __shared__ unsigned short As[32 * 264];
  __shared__ float gmax[32];
  int tid = threadIdx.x;
  int wv = tid >> 6, lane = tid & 63;
  int rowBase = blockIdx.x * 32, gn0 = rowBase >> 3;
  int bb = lane >> 3, fo = (lane & 7) << 4;
  int node8 = wv >> 1, half = wv & 1;
  int n = gn0 + node8;
  int e0 = offs[n], e1 = offs[n + 1];   // metadata first (overlaps staging)
  // stage A1 (xin) into cols 0..127 — one uint4 per thread
  {
    int row = tid >> 4, sub = tid & 15;
    *(uint4*)&As[row * 264 + sub * 8] =
        *(const uint4*)&A1[(size_t)(rowBase + row) * 128 + sub * 8];
  }
  float acc[16];
  gather_accum(half ? GqU : GqR, half ? sU : sR, e0, e1, csr_src, csr_w, dis, n, bb, fo, acc);
  const float* bias = bRU + half * 128 + fo;
  size_t rowSelf = ((size_t)n << 3) + bb;
  if (half == 0) {
    int lr = node8 * 8 + bb;
#pragma unroll
    for (int jj = 0; jj < 2; jj++) {
      uint4 hq = *(const uint4*)&h[rowSelf * 128 + fo + 8 * jj];
      float hv[8];
      hv[0] = bflo(hq.x); hv[1] = bfhi(hq.x); hv[2] = bflo(hq.y); hv[3] = bfhi(hq.y);
      hv[4] = bflo(hq.z); hv[5] = bfhi(hq.z); hv[6] = bflo(hq.w); hv[7] = bfhi(hq.w);
      unsigned ow[4];
#pragma unroll
      for (int d = 0; d < 4; d++) {
        float s0 = 1.0f / (1.0f + __expf(-(acc[8 * jj + 2 * d]     + bias[8 * jj + 2 * d])));
        float s1 = 1.0f / (1.0f + __expf(-(acc[8 * jj + 2 * d + 1] + bias[8 * jj + 2 * d + 1])));
        ow[d] = (unsigned)f2bf(s0 * hv[2 * d]) | ((unsigned)f2bf(s1 * hv[2 * d + 1]) << 16);
      }
      uint4 o; o.x = ow[0]; o.y = ow[1]; o.z = ow[2]; o.w = ow[3];
      *(uint4*)&As[lr * 264 + 128 + fo + 8 * jj] = o;
    }
  } else {
#pragma unroll
    for (int jj = 0; jj < 2; jj++) {
      unsigned ow[4];
#pragma unroll
      for (int d = 0; d < 4; d++) {
        float s0 = 1.0f / (1.0f + __expf(-(acc[8 * jj + 2 * d]     + bias[8 * jj + 2 * d])));
        float s1 = 1.0f / (1.0f + __expf(-(acc[8 * jj + 2 * d + 1] + bias[8 * jj + 2 * d + 1])));
        ow[d] = (unsigned)f2bf(s0) | ((unsigned)f2bf(s1) << 16);
      }
      uint4 o; o.x = ow[0]; o.y = ow[1]; o.z = ow[2]; o.w = ow[3];
      *(uint4*)&u_out[rowSelf * 128 + fo + 8 * jj] = o;
    }
  }
  __syncthreads();
  gemm_body<2, 1, 1, 512>(As, gmax, Wp, Cq, Cq, sC, sC, rowBase, tid);
}

// ---------------- FUSED C: cand-gather + GRU prologue + gates GEMM ----------------
// Waves 0-3: full-degree cand-gather node wv, GRU (u from global) -> h + LDS A1.
// Waves 4-7: stage A2 (other layer's state).

__global__ __launch_bounds__(512, 8) void fused_gates_q(
    const signed char* __restrict__ Cq, const float* __restrict__ sC,
    const int* __restrict__ offs, const int* __restrict__ csr_src,
    const float* __restrict__ csr_w, const float* __restrict__ dis,
    const float* __restrict__ bC, const unsigned short* __restrict__ u_in,
    unsigned short* __restrict__ h_io,
    const unsigned short* __restrict__ A2src, const unsigned short* __restrict__ Wp,
    signed char* __restrict__ GqRo, signed char* __restrict__ GqUo,
    float* __restrict__ sRo, float* __restrict__ sUo) {
  __shared__ unsigned short As[32 * 264];
  __shared__ float gmax[32];
  int tid = threadIdx.x;
  int wv = tid >> 6, lane = tid & 63;
  int rowBase = blockIdx.x * 32, gn0 = rowBase >> 3;
  int bb = lane >> 3, fo = (lane & 7) << 4;
  if (wv >= 4) {
    int t2 = tid - 256;
    for (int c = t2; c < 512; c += 256) {
      int row = c >> 4, sub = c & 15;
      *(uint4*)&As[row * 264 + 128 + sub * 8] =
          *(const uint4*)&A2src[(size_t)(rowBase + row) * 128 + sub * 8];
    }
  } else {
    int node8 = wv;
    int n = gn0 + node8;
    int e0 = offs[n], e1 = offs[n + 1];
    float acc[16];
    gather_accum(Cq, sC, e0, e1, csr_src, csr_w, dis, n, bb, fo, acc);
    size_t rowSelf = ((size_t)n << 3) + bb;
    uint4 o0, o1;
    gru_combine_store(acc, bC + fo, u_in, h_io, rowSelf, fo, o0, o1);
    int lr = node8 * 8 + bb;
    *(uint4*)&As[lr * 264 + fo] = o0;
    *(uint4*)&As[lr * 264 + fo + 8] = o1;
  }
  __syncthreads();
  gemm_body<2, 2, 2, 512>(As, gmax, Wp, GqRo, GqUo, sRo, sUo, rowBase, tid);
}

// ---------------- FUSED E: cand-gather h1 GRU + lin_in(t+1) + gates0 GEMM ----------
// Waves 0-3: cand-gather node wv, GRU (u from global) -> h1 global.
// Waves 4-7: stage A2 (h0) + lin_in(t+1) -> LDS A1 + global xt.

__global__ __launch_bounds__(512, 8) void fused_gates_lin_q(
    const signed char* __restrict__ Cq, const float* __restrict__ sC,
    const int* __restrict__ offs, const int* __restrict__ csr_src,
    const float* __restrict__ csr_w, const float* __restrict__ dis,
    const float* __restrict__ bC, const unsigned short* __restrict__ u_in,
    unsigned short* __restrict__ h_io,
    const float* __restrict__ x_seq, const float* __restrict__ Win,
    const float* __restrict__ bin, unsigned short* __restrict__ xt_out,
    const unsigned short* __restrict__ A2src, const unsigned short* __restrict__ Wp,
    signed char* __restrict__ GqRo, signed char* __restrict__ GqUo,
    float* __restrict__ sRo, float* __restrict__ sUo, int t_next) {
  __shared__ unsigned short As[32 * 264];
  __shared__ float gmax[32];
  int tid = threadIdx.x;
  int wv = tid >> 6, lane = tid & 63;
  int rowBase = blockIdx.x * 32, gn0 = rowBase >> 3;
  int bb = lane >> 3, fo = (lane & 7) << 4;
  if (wv < 4) {
    int node8 = wv;
    int n = gn0 + node8;
    int e0 = offs[n], e1 = offs[n + 1];
    float acc[16];
    gather_accum(Cq, sC, e0, e1, csr_src, csr_w, dis, n, bb, fo, acc);
    size_t rowSelf = ((size_t)n << 3) + bb;
    uint4 o0, o1;
    gru_combine_store(acc, bC + fo, u_in, h_io, rowSelf, fo, o0, o1);
  } else {
    int t2 = tid - 256;
    // stage A2 (h0) into cols 128..255
    for (int c = t2; c < 512; c += 256) {
      int row = c >> 4, sub = c & 15;
      *(uint4*)&As[row * 264 + 128 + sub * 8] =
          *(const uint4*)&A2src[(size_t)(rowBase + row) * 128 + sub * 8];
    }
    // lin_in for t_next: 32 rows x 16 fh-units -> LDS cols 0..127 + global xt
    for (int c = t2; c < 512; c += 256) {
      int row = c >> 4, fh = c & 15;
      int grow = rowBase + row;
      int n2 = grow >> 3, bbv = grow & 7;
      const float* xp = x_seq + (((size_t)bbv * SS + t_next) * NN + n2) * FF;
      float4 a0 = *(const float4*)&bin[fh * 8];
      float4 a1 = *(const float4*)&bin[fh * 8 + 4];
#pragma unroll
      for (int ff = 0; ff < FF; ff++) {
        float xv = xp[ff];
        float4 w0 = *(const float4*)&Win[ff * HH + fh * 8];
        float4 w1 = *(const float4*)&Win[ff * HH + fh * 8 + 4];
        a0.x += xv * w0.x; a0.y += xv * w0.y; a0.z += xv * w0.z; a0.w += xv * w0.w;
        a1.x += xv * w1.x; a1.y += xv * w1.y; a1.z += xv * w1.z; a1.w += xv * w1.w;
      }
      uint4 o;
      o.x = (unsigned)f2bf(fmaxf(a0.x, 0.f)) | ((unsigned)f2bf(fmaxf(a0.y, 0.f)) << 16);
      o.y = (unsigned)f2bf(fmaxf(a0.z, 0.f)) | ((unsigned)f2bf(fmaxf(a0.w, 0.f)) << 16);
      o.z = (unsigned)f2bf(fmaxf(a1.x, 0.f)) | ((unsigned)f2bf(fmaxf(a1.y, 0.f)) << 16);
      o.w = (unsigned)f2bf(fmaxf(a1.z, 0.f)) | ((unsigned)f2bf(fmaxf(a1.w, 0.f)) << 16);
      *(uint4*)&As[row * 264 + fh * 8] = o;
      *(uint4*)&xt_out[(size_t)grow * 128 + fh * 8] = o;
    }
  }
  __syncthreads();
  gemm_body<2, 2, 2, 512>(As, gmax, Wp, GqRo, GqUo, sRo, sUo, rowBase, tid);
}

// ---------------- final candidate aggregation + GRU update (t = S-1, layer 1) --------

__global__ __launch_bounds__(256) void scatter_c_update_q(
    const signed char* __restrict__ Cq, const float* __restrict__ sC,
    const int* __restrict__ offs, const int* __restrict__ csr_src,
    const float* __restrict__ csr_w, const float* __restrict__ dis,
    const float* __restrict__ bC, const unsigned short* __restrict__ u,
    unsigned short* __restrict__ h) {
  int tid = threadIdx.x;
  int wv = tid >> 6, lane = tid & 63;
  int n = blockIdx.x * 4 + wv;
  int bb = lane >> 3;
  int fo = (lane & 7) << 4;
  int e0 = offs[n], e1 = offs[n + 1];
  float acc[16];
  gather_accum(Cq, sC, e0, e1, csr_src, csr_w, dis, n, bb, fo, acc);
  size_t rowSelf = (size_t)(n << 3) + bb;
  uint4 o0, o1;
  gru_combine_store(acc, bC + fo, u, h, rowSelf, fo, o0, o1);
}

// ---------------- BatchNorm stats ----------------

__global__ __launch_bounds__(256) void bn_stats_kernel(const unsigned short* __restrict__ h,
                                                       float* __restrict__ sums) {
  __shared__ float ls[512];
  int tid = threadIdx.x;
  float s = 0.f, sq = 0.f;
  for (size_t idx = (size_t)blockIdx.x * 256 + tid; idx < (size_t)TOTAL * HH;
       idx += (size_t)gridDim.x * 256) {
    float v = bf2f(h[idx]);
    s += v; sq += v * v;
  }
  ls[tid] = s; ls[256 + tid] = sq;
  __syncthreads();
  if (tid < 128) {
    atomicAdd(&sums[tid], ls[tid] + ls[tid + 128]);
    atomicAdd(&sums[128 + tid], ls[256 + tid] + ls[256 + tid + 128]);
  }
}

// ---------------- fused BN -> relu -> lin_out -> log_softmax ----------------

__global__ __launch_bounds__(256) void final_kernel(const unsigned short* __restrict__ h,
                                                    const float* __restrict__ sums,
                                                    const float* __restrict__ gamma,
                                                    const float* __restrict__ beta,
                                                    const float* __restrict__ Wout,
                                                    const float* __restrict__ bout,
                                                    float* __restrict__ out) {
  int wid = threadIdx.x >> 6, lane = threadIdx.x & 63;
  int row = blockIdx.x * 4 + wid; // node-row (n*8+bb order)
  if (row >= TOTAL) return;
  const float inv = 1.0f / (float)TOTAL;
  float p0 = 0.f, p1 = 0.f, p2 = 0.f, p3 = 0.f;
#pragma unroll
  for (int jj = 0; jj < 2; jj++) {
    int j = lane + jj * 64;
    float mean = sums[j] * inv;
    float var = sums[128 + j] * inv - mean * mean;
    float hn = (bf2f(h[(size_t)row * HH + j]) - mean) * rsqrtf(var + 1e-5f) * gamma[j] + beta[j];
    hn = fmaxf(hn, 0.0f);
    p0 += hn * Wout[j * 4 + 0];
    p1 += hn * Wout[j * 4 + 1];
    p2 += hn * Wout[j * 4 + 2];
    p3 += hn * Wout[j * 4 + 3];
  }
  for (int off = 32; off; off >>= 1) {
    p0 += __shfl_down(p0, off);
    p1 += __shfl_down(p1, off);
    p2 += __shfl_down(p2, off);
    p3 += __shfl_down(p3, off);
  }
  if (lane == 0) {
    p0 += bout[0]; p1 += bout[1]; p2 += bout[2]; p3 += bout[3];
    float m = fmaxf(fmaxf(p0, p1), fmaxf(p2, p3));
    float e = __expf(p0 - m) + __expf(p1 - m) + __expf(p2 - m) + __expf(p3 - m);
    float lse = m + __logf(e);
    int bb = row & 7, n = row >> 3;
    float* o = out + ((size_t)bb * NN + n) * 4;
    o[0] = p0 - lse; o[1] = p1 - lse; o[2] = p2 - lse; o[3] = p3 - lse;
  }
}

// ---------------- launcher ----------------

extern "C" void kernel_launch(void* const* d_in, const int* in_sizes, int n_in,
                              void* d_out, int out_size, void* d_ws, size_t ws_size,
                              hipStream_t stream) {
  const float* x_seq = (const float*)d_in[0];
  const int* ei      = (const int*)d_in[1];
  const float* ew    = (const float*)d_in[2];
  const float* Win   = (const float*)d_in[3];
  const float* bin   = (const float*)d_in[4];
  const float* convW = (const float*)d_in[5];
  const float* convB = (const float*)d_in[6];
  const float* gamma = (const float*)d_in[7];
  const float* beta  = (const float*)d_in[8];
  const float* Wout  = (const float*)d_in[9];
  const float* bout  = (const float*)d_in[10];
  float* out = (float*)d_out;

  char* ws = (char*)d_ws;
  size_t off = 0;
  auto alloc = [&](size_t bytes) {
    void* p = ws + off;
    off += (bytes + 1023) & ~(size_t)1023;
    return p;
  };
  float* deg     = (float*)alloc(NN * 4);
  float* dis     = (float*)alloc(NN * 4);
  int*   cnt     = (int*)alloc(NN * 4);
  int*   offs    = (int*)alloc((NN + 1) * 4);
  int*   cursor  = (int*)alloc(NN * 4);
  int*   csr_src = (int*)alloc(EE * 4);
  float* csr_w   = (float*)alloc(EE * 4);
  float* sums    = (float*)alloc(256 * 4);
  float* sR      = (float*)alloc(NN * 4);
  float* sU      = (float*)alloc(NN * 4);
  float* sC      = (float*)alloc(NN * 4);
  unsigned short* Wp = (unsigned short*)alloc(6 * 32768 * 2);  // packed conv weights
  const size_t NH = (size_t)TOTAL * HH; // 5,120,000
  unsigned short* h0 = (unsigned short*)alloc(NH * 2);
  unsigned short* h1 = (unsigned short*)alloc(NH * 2);
  unsigned short* xt = (unsigned short*)alloc(NH * 2);
  unsigned short* ub = (unsigned short*)alloc(NH * 2);
  signed char* GqR = (signed char*)alloc(NH);   // int8 messages
  signed char* GqU = (signed char*)alloc(NH);
  signed char* Cq  = (signed char*)alloc(NH);   // DEDICATED (no alias with GqR!)

  hipMemsetAsync(deg, 0, NN * 4, stream);
  hipMemsetAsync(cnt, 0, NN * 4, stream);
  hipMemsetAsync(cursor, 0, NN * 4, stream);
  hipMemsetAsync(sums, 0, 256 * 4, stream);
  hipMemsetAsync(h0, 0, NH * 2, stream);
  hipMemsetAsync(h1, 0, NH * 2, stream);

  deg_cnt_kernel<<<(EE + 255) / 256, 256, 0, stream>>>(ei, ew, deg, cnt);
  dis_kernel<<<(NN + 255) / 256, 256, 0, stream>>>(deg, dis);
  scan_kernel<<<1, 256, 0, stream>>>(cnt, offs);
  fill_csr_kernel<<<(EE + 255) / 256, 256, 0, stream>>>(ei, ew, dis, offs, cursor, csr_src, csr_w);
  prepack_kernel<<<24576 / 256, 256, 0, stream>>>(convW, Wp);

  const unsigned short* Wg0 = Wp;
  const unsigned short* Wc0 = Wp + (size_t)2 * 32768;
  const unsigned short* Wg1 = Wp + (size_t)3 * 32768;
  const unsigned short* Wc1 = Wp + (size_t)5 * 32768;
  const float* bRU0 = convB;
  const float* bC0  = convB + 2 * HH;
  const float* bRU1 = convB + 3 * HH;
  const float* bC1  = convB + 5 * HH;

  // bootstrap: xt(t=0), gates0(t=0)
  lin_in_kernel<<<TOTAL * 16 / 256, 256, 0, stream>>>(x_seq, Win, bin, xt, 0);
  gemm_mfma_q<2, 2><<<TOTAL / 32, 512, 0, stream>>>(xt, h0, Wg0, GqR, GqU, sR, sU);

  for (int t = 0; t < SS; t++) {
    // B: gates0-gather -> rh0(LDS), u0 -> cand0 GEMM -> Cq
    fused_cand_q<<<TOTAL / 32, 512, 0, stream>>>(GqR, GqU, sR, sU, offs, csr_src, csr_w,
                                                 dis, bRU0, h0, ub, xt, Wc0, Cq, sC);
    // C: cand0-gather -> h0 update (global+LDS A1) -> gates1 GEMM -> GqR/GqU
    fused_gates_q<<<TOTAL / 32, 512, 0, stream>>>(Cq, sC, offs, csr_src, csr_w, dis,
                                                  bC0, ub, h0, h1, Wg1, GqR, GqU, sR, sU);
    // D: gates1-gather -> rh1(LDS), u1 -> cand1 GEMM -> Cq
    fused_cand_q<<<TOTAL / 32, 512, 0, stream>>>(GqR, GqU, sR, sU, offs, csr_src, csr_w,
                                                 dis, bRU1, h1, ub, h0, Wc1, Cq, sC);
    // E: cand1-gather -> h1 update; lin_in(t+1) -> xt; gates0 GEMM -> GqR/GqU
    if (t < SS - 1) {
      fused_gates_lin_q<<<TOTAL / 32, 512, 0, stream>>>(Cq, sC, offs, csr_src, csr_w, dis,
                                                        bC1, ub, h1, x_seq, Win, bin, xt,
                                                        h0, Wg0, GqR, GqU, sR, sU, t + 1);
    } else {
      scatter_c_update_q<<<NN / 4, 256, 0, stream>>>(Cq, sC, offs, csr_src, csr_w,
                                                     dis, bC1, ub, h1);
    }
  }

  bn_stats_kernel<<<256, 256, 0, stream>>>(h1, sums);
  final_kernel<<<TOTAL / 4, 256, 0, stream>>>(h1, sums, gamma, beta, Wout, bout, out);
}